// Round 1
// baseline (4517.050 us; speedup 1.0000x reference)
//
#include <hip/hip_runtime.h>
#include <math.h>

#define N_PTS   131072
#define HDIM    256      // hidden width
#define PTS     16       // points per block
#define NTHR    256      // threads per block
#define FSLICE  16       // features per thread (4 groups of 4, strided 64)
#define KC      32       // K-chunk staged in LDS
#define HPAD    260      // padded LDS row stride in dwords (bank spread)

#define K_CONST 0.005f
#define D_U     0.001f
#define D_V     0.005f

// Streams: 0=value, 1=d/dt, 2=d/dx, 3=d/dy, 4=d2/dx2, 5=d2/dy2

__global__ __launch_bounds__(NTHR, 1)
void pinn_diffreact_f32(const float* __restrict__ t_in,
                        const float* __restrict__ x_in,
                        const float* __restrict__ y_in,
                        const float* __restrict__ W0, const float* __restrict__ b0,
                        const float* __restrict__ W1, const float* __restrict__ b1,
                        const float* __restrict__ W2, const float* __restrict__ b2,
                        const float* __restrict__ W3, const float* __restrict__ b3,
                        const float* __restrict__ W4, const float* __restrict__ b4,
                        float* __restrict__ out)
{
    __shared__ float Hs[6 * PTS * HPAD];   // 6*16*260*4 = 99840 B
    __shared__ float Wc[KC * HDIM];        // 32*256*4  = 32768 B

    const int tid   = threadIdx.x;
    const int pt    = tid >> 4;            // 0..15 point within block
    const int fbase = (tid & 15) * 4;      // feature slice: fbase + jv*64 + q
    const int gpt   = blockIdx.x * PTS + pt;

    // ---------------- layer 0: 3 -> 256 ----------------
    {
        const float tv = t_in[gpt], xv = x_in[gpt], yv = y_in[gpt];
        #pragma unroll
        for (int jv = 0; jv < 4; ++jv) {
            #pragma unroll
            for (int q = 0; q < 4; ++q) {
                const int f = fbase + jv * 64 + q;
                const float w0 = W0[0 * HDIM + f];
                const float w1 = W0[1 * HDIM + f];
                const float w2 = W0[2 * HDIM + f];
                const float z  = tv * w0 + xv * w1 + yv * w2 + b0[f];
                const float a  = tanhf(z);
                const float g  = 1.f - a * a;
                Hs[(0 * PTS + pt) * HPAD + f] = a;
                Hs[(1 * PTS + pt) * HPAD + f] = g * w0;            // a_t (z_t = w0)
                Hs[(2 * PTS + pt) * HPAD + f] = g * w1;            // a_x
                Hs[(3 * PTS + pt) * HPAD + f] = g * w2;            // a_y
                Hs[(4 * PTS + pt) * HPAD + f] = -2.f * a * g * w1 * w1; // a_xx (z_xx=0)
                Hs[(5 * PTS + pt) * HPAD + f] = -2.f * a * g * w2 * w2; // a_yy
            }
        }
    }
    __syncthreads();

    // ---------------- layers 1..3: 256 -> 256 ----------------
    const float* Ws[3] = {W1, W2, W3};
    const float* bs[3] = {b1, b2, b3};

    for (int L = 0; L < 3; ++L) {
        const float* __restrict__ W = Ws[L];
        const float* __restrict__ b = bs[L];

        float acc[6][FSLICE];
        #pragma unroll
        for (int s = 0; s < 6; ++s)
            #pragma unroll
            for (int j = 0; j < FSLICE; ++j) acc[s][j] = 0.f;

        for (int kc = 0; kc < HDIM / KC; ++kc) {
            __syncthreads();  // previous chunk's Wc reads complete
            {   // stage W[kc*KC .. kc*KC+KC)[0..256) into LDS, coalesced float4
                const float4* src = (const float4*)(W + kc * KC * HDIM);
                float4* dst = (float4*)Wc;
                #pragma unroll
                for (int i = 0; i < (KC * HDIM / 4) / NTHR; ++i)
                    dst[tid + i * NTHR] = src[tid + i * NTHR];
            }
            __syncthreads();

            #pragma unroll
            for (int k4 = 0; k4 < KC; k4 += 4) {
                float4 h[6];
                #pragma unroll
                for (int s = 0; s < 6; ++s)
                    h[s] = *(const float4*)&Hs[(s * PTS + pt) * HPAD + kc * KC + k4];

                #pragma unroll
                for (int q = 0; q < 4; ++q) {
                    const float hv[6] = {
                        q == 0 ? h[0].x : q == 1 ? h[0].y : q == 2 ? h[0].z : h[0].w,
                        q == 0 ? h[1].x : q == 1 ? h[1].y : q == 2 ? h[1].z : h[1].w,
                        q == 0 ? h[2].x : q == 1 ? h[2].y : q == 2 ? h[2].z : h[2].w,
                        q == 0 ? h[3].x : q == 1 ? h[3].y : q == 2 ? h[3].z : h[3].w,
                        q == 0 ? h[4].x : q == 1 ? h[4].y : q == 2 ? h[4].z : h[4].w,
                        q == 0 ? h[5].x : q == 1 ? h[5].y : q == 2 ? h[5].z : h[5].w
                    };
                    #pragma unroll
                    for (int jv = 0; jv < 4; ++jv) {
                        const float4 w = *(const float4*)&Wc[(k4 + q) * HDIM + fbase + jv * 64];
                        const float wv[4] = {w.x, w.y, w.z, w.w};
                        #pragma unroll
                        for (int r = 0; r < 4; ++r) {
                            const int j = jv * 4 + r;
                            #pragma unroll
                            for (int s = 0; s < 6; ++s)
                                acc[s][j] += hv[s] * wv[r];
                        }
                    }
                }
            }
        }
        __syncthreads();  // all Hs reads of this layer done

        // tanh coupling + write back
        #pragma unroll
        for (int jv = 0; jv < 4; ++jv) {
            #pragma unroll
            for (int q = 0; q < 4; ++q) {
                const int j = jv * 4 + q;
                const int f = fbase + jv * 64 + q;
                const float z   = acc[0][j] + b[f];
                const float a   = tanhf(z);
                const float g   = 1.f - a * a;
                const float zt  = acc[1][j], zx = acc[2][j], zy = acc[3][j];
                const float zxx = acc[4][j], zyy = acc[5][j];
                Hs[(0 * PTS + pt) * HPAD + f] = a;
                Hs[(1 * PTS + pt) * HPAD + f] = g * zt;
                Hs[(2 * PTS + pt) * HPAD + f] = g * zx;
                Hs[(3 * PTS + pt) * HPAD + f] = g * zy;
                Hs[(4 * PTS + pt) * HPAD + f] = g * zxx - 2.f * a * g * zx * zx;
                Hs[(5 * PTS + pt) * HPAD + f] = g * zyy - 2.f * a * g * zy * zy;
            }
        }
        __syncthreads();
    }

    // ---------------- layer 4: 256 -> 2, linear ----------------
    float p[6][2];
    #pragma unroll
    for (int s = 0; s < 6; ++s) { p[s][0] = 0.f; p[s][1] = 0.f; }

    #pragma unroll
    for (int jv = 0; jv < 4; ++jv) {
        #pragma unroll
        for (int q = 0; q < 4; ++q) {
            const int f = fbase + jv * 64 + q;
            const float w0 = W4[f * 2 + 0];
            const float w1 = W4[f * 2 + 1];
            #pragma unroll
            for (int s = 0; s < 6; ++s) {
                const float hv = Hs[(s * PTS + pt) * HPAD + f];
                p[s][0] += hv * w0;
                p[s][1] += hv * w1;
            }
        }
    }
    // reduce across the 16 lanes sharing this point (lanes tid&15)
    #pragma unroll
    for (int m = 1; m < 16; m <<= 1) {
        #pragma unroll
        for (int s = 0; s < 6; ++s) {
            p[s][0] += __shfl_xor(p[s][0], m);
            p[s][1] += __shfl_xor(p[s][1], m);
        }
    }

    if ((tid & 15) == 0) {
        const float u   = p[0][0] + b4[0];
        const float v   = p[0][1] + b4[1];
        const float ut  = p[1][0], vt  = p[1][1];
        const float uxx = p[4][0], vxx = p[4][1];
        const float uyy = p[5][0], vyy = p[5][1];
        const float fo = u - u * u * u - K_CONST - v + D_U * (uxx + uyy) - ut;
        const float go = u - v + D_V * (vxx + vyy) - vt;
        out[0 * N_PTS + gpt] = u;
        out[1 * N_PTS + gpt] = v;
        out[2 * N_PTS + gpt] = fo;
        out[3 * N_PTS + gpt] = go;
    }
}

extern "C" void kernel_launch(void* const* d_in, const int* in_sizes, int n_in,
                              void* d_out, int out_size, void* d_ws, size_t ws_size,
                              hipStream_t stream)
{
    const float* t_in = (const float*)d_in[0];
    const float* x_in = (const float*)d_in[1];
    const float* y_in = (const float*)d_in[2];
    const float* W0 = (const float*)d_in[3];
    const float* b0 = (const float*)d_in[4];
    const float* W1 = (const float*)d_in[5];
    const float* b1 = (const float*)d_in[6];
    const float* W2 = (const float*)d_in[7];
    const float* b2 = (const float*)d_in[8];
    const float* W3 = (const float*)d_in[9];
    const float* b3 = (const float*)d_in[10];
    const float* W4 = (const float*)d_in[11];
    const float* b4 = (const float*)d_in[12];
    float* out = (float*)d_out;

    dim3 grid(N_PTS / PTS), block(NTHR);
    hipLaunchKernelGGL(pinn_diffreact_f32, grid, block, 0, stream,
                       t_in, x_in, y_in, W0, b0, W1, b1, W2, b2, W3, b3, W4, b4, out);
}

// Round 2
// 907.033 us; speedup vs baseline: 4.9800x; 4.9800x over previous
//
#include <hip/hip_runtime.h>
#include <math.h>

#define N_PTS   131072
#define K_CONST 0.005f
#define D_U     0.001f
#define D_V     0.005f

typedef unsigned short u16;
typedef __attribute__((ext_vector_type(8))) short  bf16x8;
typedef __attribute__((ext_vector_type(4))) float  f32x4;
typedef __attribute__((ext_vector_type(4))) u16    u16x4;
typedef __attribute__((ext_vector_type(8))) u16    u16x8;

__device__ __forceinline__ u16 f2bf(float x){
    unsigned u = __float_as_uint(x);
    unsigned r = (u + 0x7FFFu + ((u >> 16) & 1u)) >> 16;
    return (u16)r;
}
__device__ __forceinline__ float bf2f(u16 h){ return __uint_as_float(((unsigned)h) << 16); }

// ---------------- prep: split W1..W3 into bf16 hi/lo, W^T fragment layout ----------------
// layout: idx = (((L*8 + ks)*16 + nt)*64 + lane)*8 + j
// value  = W[k][n], k = ks*32 + (lane>>4)*8 + j, n = nt*16 + (lane&15)
__global__ void prep_weights(const float* __restrict__ W1, const float* __restrict__ W2,
                             const float* __restrict__ W3,
                             u16* __restrict__ wsHi, u16* __restrict__ wsLo)
{
    int gid  = blockIdx.x * 256 + threadIdx.x;   // 0 .. 24575
    int lane = gid & 63;
    int nt   = (gid >> 6) & 15;
    int ks   = (gid >> 10) & 7;
    int L    = gid >> 13;
    if (L >= 3) return;
    const float* W = (L == 0) ? W1 : ((L == 1) ? W2 : W3);
    int n  = nt * 16 + (lane & 15);
    int kg = lane >> 4;
    u16 hi[8], lo[8];
    #pragma unroll
    for (int j = 0; j < 8; ++j) {
        int k = ks * 32 + kg * 8 + j;
        float wv = W[k * 256 + n];
        u16 h = f2bf(wv);
        hi[j] = h;
        lo[j] = f2bf(wv - bf2f(h));
    }
    *(u16x8*)&wsHi[(size_t)gid * 8] = *(u16x8*)hi;
    *(u16x8*)&wsLo[(size_t)gid * 8] = *(u16x8*)lo;
}

// ---------------- main fused kernel ----------------
// Block: 8 points. LDS activations H[m][k]: m = stream*8 + pt (48 rows), k = feature (256),
// stored bf16 hi/lo with XOR swizzle: byte = m*512 + ((2k) ^ ((m&7)<<4)).
// GEMM (per hidden layer): Z^T[n][m] = sum_k W[k][n] * H[m][k] via
// mfma(A=W^T frag (global), B=H frag (LDS)).  C: row=n-in-tile=(lane>>4)*4+r, col=m-in-tile=lane&15.
__global__ __launch_bounds__(256, 3)
void pinn_mfma(const float* __restrict__ t_in, const float* __restrict__ x_in,
               const float* __restrict__ y_in,
               const float* __restrict__ W0, const float* __restrict__ b0,
               const float* __restrict__ b1, const float* __restrict__ b2,
               const float* __restrict__ b3,
               const float* __restrict__ W4, const float* __restrict__ b4,
               const u16* __restrict__ wsHi, const u16* __restrict__ wsLo,
               float* __restrict__ out)
{
    __shared__ u16  Ahi[48 * 256];   // 24 KB
    __shared__ u16  Alo[48 * 256];   // 24 KB
    __shared__ float txy[24];

    const int tid  = threadIdx.x;
    const int lane = tid & 63;
    const int wv   = tid >> 6;       // wave 0..3

    if (tid < 24) {
        int which = tid >> 3, pt = tid & 7;
        const float* s = (which == 0) ? t_in : ((which == 1) ? x_in : y_in);
        txy[tid] = s[blockIdx.x * 8 + pt];
    }
    __syncthreads();

    // ---- layer 0: 3 -> 256 (direct, fp32) ----
    {
        int pt = tid >> 5;           // 0..7
        int i  = tid & 31;
        int n0 = i * 8;
        float tv = txy[pt], xv = txy[8 + pt], yv = txy[16 + pt];
        float w0[8], w1[8], w2[8], bb[8];
        #pragma unroll
        for (int q = 0; q < 2; ++q) {
            *(float4*)&w0[q*4] = *(const float4*)&W0[0*256 + n0 + q*4];
            *(float4*)&w1[q*4] = *(const float4*)&W0[1*256 + n0 + q*4];
            *(float4*)&w2[q*4] = *(const float4*)&W0[2*256 + n0 + q*4];
            *(float4*)&bb[q*4] = *(const float4*)&b0[n0 + q*4];
        }
        float sv[6][8];
        #pragma unroll
        for (int j = 0; j < 8; ++j) {
            float z = tv*w0[j] + xv*w1[j] + yv*w2[j] + bb[j];
            float a = tanhf(z);
            float g = 1.f - a*a;
            sv[0][j] = a;
            sv[1][j] = g * w0[j];
            sv[2][j] = g * w1[j];
            sv[3][j] = g * w2[j];
            sv[4][j] = -2.f * a * g * w1[j] * w1[j];
            sv[5][j] = -2.f * a * g * w2[j] * w2[j];
        }
        #pragma unroll
        for (int s = 0; s < 6; ++s) {
            u16 hi[8], lo[8];
            #pragma unroll
            for (int j = 0; j < 8; ++j) {
                hi[j] = f2bf(sv[s][j]);
                lo[j] = f2bf(sv[s][j] - bf2f(hi[j]));
            }
            int m = s * 8 + pt;
            int byteoff = m * 512 + ((2 * n0) ^ (pt << 4));
            *(u16x8*)((char*)Ahi + byteoff) = *(u16x8*)hi;
            *(u16x8*)((char*)Alo + byteoff) = *(u16x8*)lo;
        }
    }
    __syncthreads();

    // ---- layers 1..3: 256 -> 256 via split-bf16 MFMA ----
    const int hrow  = lane & 15;          // m within tile
    const int hkg   = lane >> 4;          // k-group / C-row group
    const int cpt   = lane & 7;           // point (coupling)
    const int cside = (lane >> 3) & 1;    // 0: streams {0,2,4}, 1: {1,3,5}

    #pragma unroll 1
    for (int L = 0; L < 3; ++L) {
        const float* bL = (L == 0) ? b1 : ((L == 1) ? b2 : b3);

        f32x4 acc[3][4];
        #pragma unroll
        for (int mt = 0; mt < 3; ++mt)
            #pragma unroll
            for (int nt = 0; nt < 4; ++nt)
                acc[mt][nt] = (f32x4){0.f, 0.f, 0.f, 0.f};

        #pragma unroll 1
        for (int ks = 0; ks < 8; ++ks) {
            bf16x8 wh[4], wl[4];
            #pragma unroll
            for (int nt = 0; nt < 4; ++nt) {
                int idx = ((((L * 8 + ks) * 16) + (wv * 4 + nt)) * 64 + lane) * 8;
                wh[nt] = *(const bf16x8*)&wsHi[idx];
                wl[nt] = *(const bf16x8*)&wsLo[idx];
            }
            bf16x8 hh[3], hl[3];
            int koff = (64 * ks + 16 * hkg) ^ ((lane & 7) << 4);
            #pragma unroll
            for (int mt = 0; mt < 3; ++mt) {
                int byteoff = (hrow + 16 * mt) * 512 + koff;
                hh[mt] = *(bf16x8*)((char*)Ahi + byteoff);
                hl[mt] = *(bf16x8*)((char*)Alo + byteoff);
            }
            #pragma unroll
            for (int nt = 0; nt < 4; ++nt) {
                #pragma unroll
                for (int mt = 0; mt < 3; ++mt) {
                    acc[mt][nt] = __builtin_amdgcn_mfma_f32_16x16x32_bf16(wh[nt], hh[mt], acc[mt][nt], 0, 0, 0);
                    acc[mt][nt] = __builtin_amdgcn_mfma_f32_16x16x32_bf16(wl[nt], hh[mt], acc[mt][nt], 0, 0, 0);
                    acc[mt][nt] = __builtin_amdgcn_mfma_f32_16x16x32_bf16(wh[nt], hl[mt], acc[mt][nt], 0, 0, 0);
                }
            }
        }
        __syncthreads();   // all H reads of this layer done

        // ---- tanh coupling + write next-layer H ----
        #pragma unroll
        for (int nt = 0; nt < 4; ++nt) {
            int nbase = (wv * 4 + nt) * 16 + 4 * hkg;
            float4 bv = *(const float4*)&bL[nbase];
            float bva[4] = {bv.x, bv.y, bv.z, bv.w};
            u16 o_hi[3][4], o_lo[3][4];
            #pragma unroll
            for (int r = 0; r < 4; ++r) {
                float z0 = acc[0][nt][r] + (cside == 0 ? bva[r] : 0.f);
                float a  = tanhf(z0);
                float g  = 1.f - a * a;
                float ax = __shfl_xor(a, 8);
                float gx = __shfl_xor(g, 8);
                float au = (cside == 0) ? a : ax;
                float gu = (cside == 0) ? g : gx;
                float z1 = acc[1][nt][r];
                float z2 = acc[2][nt][r];
                float o0 = (cside == 0) ? au : gu * acc[0][nt][r];
                float o1 = gu * z1;
                float o2 = gu * z2 - 2.f * au * gu * z1 * z1;
                o_hi[0][r] = f2bf(o0); o_lo[0][r] = f2bf(o0 - bf2f(o_hi[0][r]));
                o_hi[1][r] = f2bf(o1); o_lo[1][r] = f2bf(o1 - bf2f(o_hi[1][r]));
                o_hi[2][r] = f2bf(o2); o_lo[2][r] = f2bf(o2 - bf2f(o_hi[2][r]));
            }
            #pragma unroll
            for (int j = 0; j < 3; ++j) {
                int m = 16 * j + 8 * cside + cpt;
                int byteoff = m * 512 + ((2 * nbase) ^ (cpt << 4));
                *(u16x4*)((char*)Ahi + byteoff) = *(u16x4*)o_hi[j];
                *(u16x4*)((char*)Alo + byteoff) = *(u16x4*)o_lo[j];
            }
        }
        __syncthreads();
    }

    // ---- final layer: 256 -> 2 (linear) + PDE residuals ----
    {
        int pt = tid >> 5;
        int i  = tid & 31;
        int n0 = i * 8;
        float ps[6][2];
        #pragma unroll
        for (int s = 0; s < 6; ++s) { ps[s][0] = 0.f; ps[s][1] = 0.f; }
        float w4[16];
        #pragma unroll
        for (int q = 0; q < 4; ++q)
            *(float4*)&w4[q*4] = *(const float4*)&W4[n0 * 2 + q * 4];
        #pragma unroll
        for (int s = 0; s < 6; ++s) {
            int m = s * 8 + pt;
            int byteoff = m * 512 + ((2 * n0) ^ (pt << 4));
            u16x8 hv = *(u16x8*)((char*)Ahi + byteoff);
            u16x8 lv = *(u16x8*)((char*)Alo + byteoff);
            #pragma unroll
            for (int j = 0; j < 8; ++j) {
                float h = bf2f(hv[j]) + bf2f(lv[j]);
                ps[s][0] += h * w4[2*j];
                ps[s][1] += h * w4[2*j + 1];
            }
        }
        #pragma unroll
        for (int msk = 16; msk >= 1; msk >>= 1) {
            #pragma unroll
            for (int s = 0; s < 6; ++s) {
                ps[s][0] += __shfl_xor(ps[s][0], msk);
                ps[s][1] += __shfl_xor(ps[s][1], msk);
            }
        }
        if (i == 0) {
            float u  = ps[0][0] + b4[0];
            float v  = ps[0][1] + b4[1];
            float ut = ps[1][0], vt = ps[1][1];
            float uxx = ps[4][0], vxx = ps[4][1];
            float uyy = ps[5][0], vyy = ps[5][1];
            int gpt = blockIdx.x * 8 + pt;
            float fo = u - u*u*u - K_CONST - v + D_U * (uxx + uyy) - ut;
            float go = u - v + D_V * (vxx + vyy) - vt;
            out[0 * N_PTS + gpt] = u;
            out[1 * N_PTS + gpt] = v;
            out[2 * N_PTS + gpt] = fo;
            out[3 * N_PTS + gpt] = go;
        }
    }
}

// ---------------- fallback (round-1 fp32 kernel) if ws too small ----------------
#define PTS   16
#define NTHR  256
#define HDIM  256
#define KC    32
#define HPAD  260

__global__ __launch_bounds__(NTHR, 1)
void pinn_diffreact_f32(const float* __restrict__ t_in, const float* __restrict__ x_in,
                        const float* __restrict__ y_in,
                        const float* __restrict__ W0, const float* __restrict__ b0,
                        const float* __restrict__ W1, const float* __restrict__ b1,
                        const float* __restrict__ W2, const float* __restrict__ b2,
                        const float* __restrict__ W3, const float* __restrict__ b3,
                        const float* __restrict__ W4, const float* __restrict__ b4,
                        float* __restrict__ out)
{
    __shared__ float Hs[6 * PTS * HPAD];
    __shared__ float Wc[KC * HDIM];
    const int tid = threadIdx.x;
    const int pt = tid >> 4;
    const int fbase = (tid & 15) * 4;
    const int gpt = blockIdx.x * PTS + pt;
    {
        const float tv = t_in[gpt], xv = x_in[gpt], yv = y_in[gpt];
        #pragma unroll
        for (int jv = 0; jv < 4; ++jv)
            #pragma unroll
            for (int q = 0; q < 4; ++q) {
                const int f = fbase + jv * 64 + q;
                const float w0 = W0[f], w1 = W0[256 + f], w2 = W0[512 + f];
                const float z = tv*w0 + xv*w1 + yv*w2 + b0[f];
                const float a = tanhf(z), g = 1.f - a*a;
                Hs[(0*PTS+pt)*HPAD+f] = a;
                Hs[(1*PTS+pt)*HPAD+f] = g*w0;
                Hs[(2*PTS+pt)*HPAD+f] = g*w1;
                Hs[(3*PTS+pt)*HPAD+f] = g*w2;
                Hs[(4*PTS+pt)*HPAD+f] = -2.f*a*g*w1*w1;
                Hs[(5*PTS+pt)*HPAD+f] = -2.f*a*g*w2*w2;
            }
    }
    __syncthreads();
    const float* Ws[3] = {W1, W2, W3};
    const float* bs[3] = {b1, b2, b3};
    for (int L = 0; L < 3; ++L) {
        const float* __restrict__ W = Ws[L];
        const float* __restrict__ b = bs[L];
        float acc[6][16];
        #pragma unroll
        for (int s = 0; s < 6; ++s)
            #pragma unroll
            for (int j = 0; j < 16; ++j) acc[s][j] = 0.f;
        for (int kc = 0; kc < HDIM / KC; ++kc) {
            __syncthreads();
            const float4* src = (const float4*)(W + kc * KC * HDIM);
            float4* dst = (float4*)Wc;
            #pragma unroll
            for (int i2 = 0; i2 < (KC * HDIM / 4) / NTHR; ++i2)
                dst[tid + i2 * NTHR] = src[tid + i2 * NTHR];
            __syncthreads();
            #pragma unroll
            for (int k4 = 0; k4 < KC; k4 += 4) {
                float4 h[6];
                #pragma unroll
                for (int s = 0; s < 6; ++s)
                    h[s] = *(const float4*)&Hs[(s*PTS+pt)*HPAD + kc*KC + k4];
                #pragma unroll
                for (int q = 0; q < 4; ++q) {
                    float hv[6];
                    #pragma unroll
                    for (int s = 0; s < 6; ++s)
                        hv[s] = (q==0) ? h[s].x : (q==1) ? h[s].y : (q==2) ? h[s].z : h[s].w;
                    #pragma unroll
                    for (int jv = 0; jv < 4; ++jv) {
                        const float4 wq = *(const float4*)&Wc[(k4+q)*HDIM + fbase + jv*64];
                        const float wvv[4] = {wq.x, wq.y, wq.z, wq.w};
                        #pragma unroll
                        for (int r = 0; r < 4; ++r)
                            #pragma unroll
                            for (int s = 0; s < 6; ++s)
                                acc[s][jv*4+r] += hv[s] * wvv[r];
                    }
                }
            }
        }
        __syncthreads();
        #pragma unroll
        for (int jv = 0; jv < 4; ++jv)
            #pragma unroll
            for (int q = 0; q < 4; ++q) {
                const int j = jv*4+q, f = fbase + jv*64 + q;
                const float z = acc[0][j] + b[f];
                const float a = tanhf(z), g = 1.f - a*a;
                const float zt = acc[1][j], zx = acc[2][j], zy = acc[3][j];
                const float zxx = acc[4][j], zyy = acc[5][j];
                Hs[(0*PTS+pt)*HPAD+f] = a;
                Hs[(1*PTS+pt)*HPAD+f] = g*zt;
                Hs[(2*PTS+pt)*HPAD+f] = g*zx;
                Hs[(3*PTS+pt)*HPAD+f] = g*zy;
                Hs[(4*PTS+pt)*HPAD+f] = g*zxx - 2.f*a*g*zx*zx;
                Hs[(5*PTS+pt)*HPAD+f] = g*zyy - 2.f*a*g*zy*zy;
            }
        __syncthreads();
    }
    float p[6][2];
    #pragma unroll
    for (int s = 0; s < 6; ++s) { p[s][0] = 0.f; p[s][1] = 0.f; }
    #pragma unroll
    for (int jv = 0; jv < 4; ++jv)
        #pragma unroll
        for (int q = 0; q < 4; ++q) {
            const int f = fbase + jv*64 + q;
            const float w0 = W4[f*2], w1 = W4[f*2+1];
            #pragma unroll
            for (int s = 0; s < 6; ++s) {
                const float hv = Hs[(s*PTS+pt)*HPAD+f];
                p[s][0] += hv*w0; p[s][1] += hv*w1;
            }
        }
    #pragma unroll
    for (int m = 1; m < 16; m <<= 1)
        #pragma unroll
        for (int s = 0; s < 6; ++s) {
            p[s][0] += __shfl_xor(p[s][0], m);
            p[s][1] += __shfl_xor(p[s][1], m);
        }
    if ((tid & 15) == 0) {
        const float u = p[0][0] + b4[0];
        const float v = p[0][1] + b4[1];
        const float ut = p[1][0], vt = p[1][1];
        const float uxx = p[4][0], vxx = p[4][1];
        const float uyy = p[5][0], vyy = p[5][1];
        const float fo = u - u*u*u - K_CONST - v + D_U*(uxx+uyy) - ut;
        const float go = u - v + D_V*(vxx+vyy) - vt;
        out[0*N_PTS+gpt] = u;
        out[1*N_PTS+gpt] = v;
        out[2*N_PTS+gpt] = fo;
        out[3*N_PTS+gpt] = go;
    }
}

extern "C" void kernel_launch(void* const* d_in, const int* in_sizes, int n_in,
                              void* d_out, int out_size, void* d_ws, size_t ws_size,
                              hipStream_t stream)
{
    const float* t_in = (const float*)d_in[0];
    const float* x_in = (const float*)d_in[1];
    const float* y_in = (const float*)d_in[2];
    const float* W0 = (const float*)d_in[3];
    const float* b0 = (const float*)d_in[4];
    const float* W1 = (const float*)d_in[5];
    const float* b1 = (const float*)d_in[6];
    const float* W2 = (const float*)d_in[7];
    const float* b2 = (const float*)d_in[8];
    const float* W3 = (const float*)d_in[9];
    const float* b3 = (const float*)d_in[10];
    const float* W4 = (const float*)d_in[11];
    const float* b4 = (const float*)d_in[12];
    float* out = (float*)d_out;

    const size_t WS_NEEDED = (size_t)3 * 8 * 16 * 64 * 8 * 2 * 2;  // 786432 B
    if (ws_size >= WS_NEEDED) {
        u16* wsHi = (u16*)d_ws;
        u16* wsLo = wsHi + 196608;
        hipLaunchKernelGGL(prep_weights, dim3(96), dim3(256), 0, stream, W1, W2, W3, wsHi, wsLo);
        hipLaunchKernelGGL(pinn_mfma, dim3(N_PTS / 8), dim3(256), 0, stream,
                           t_in, x_in, y_in, W0, b0, b1, b2, b3, W4, b4, wsHi, wsLo, out);
    } else {
        hipLaunchKernelGGL(pinn_diffreact_f32, dim3(N_PTS / PTS), dim3(NTHR), 0, stream,
                           t_in, x_in, y_in, W0, b0, W1, b1, W2, b2, W3, b3, W4, b4, out);
    }
}

// Round 3
// 486.875 us; speedup vs baseline: 9.2776x; 1.8630x over previous
//
#include <hip/hip_runtime.h>
#include <math.h>

#define N_PTS   131072
#define K_CONST 0.005f
#define D_U     0.001f
#define D_V     0.005f

typedef unsigned short u16;
typedef __attribute__((ext_vector_type(8))) short  bf16x8;
typedef __attribute__((ext_vector_type(4))) float  f32x4;
typedef __attribute__((ext_vector_type(4))) u16    u16x4;
typedef __attribute__((ext_vector_type(8))) u16    u16x8;

__device__ __forceinline__ u16 f2bf(float x){
    unsigned u = __float_as_uint(x);
    unsigned r = (u + 0x7FFFu + ((u >> 16) & 1u)) >> 16;
    return (u16)r;
}
__device__ __forceinline__ float bf2f(u16 h){ return __uint_as_float(((unsigned)h) << 16); }

__device__ __forceinline__ float tanh_fast(float z){
    float e = __expf(2.f * z);
    return 1.f - 2.f * __builtin_amdgcn_rcpf(e + 1.f);
}

// ---------------- prep: split W1..W3 into bf16 hi/lo, W^T fragment layout ----------------
// layout: idx = (((L*8 + ks)*16 + ntg)*64 + lane)*8 + j
// value  = W[k][n], k = ks*32 + (lane>>4)*8 + j, n = ntg*16 + (lane&15)
__global__ void prep_weights(const float* __restrict__ W1, const float* __restrict__ W2,
                             const float* __restrict__ W3,
                             u16* __restrict__ wsHi, u16* __restrict__ wsLo)
{
    int gid  = blockIdx.x * 256 + threadIdx.x;   // 0 .. 24575
    int lane = gid & 63;
    int nt   = (gid >> 6) & 15;
    int ks   = (gid >> 10) & 7;
    int L    = gid >> 13;
    if (L >= 3) return;
    const float* W = (L == 0) ? W1 : ((L == 1) ? W2 : W3);
    int n  = nt * 16 + (lane & 15);
    int kg = lane >> 4;
    u16 hi[8], lo[8];
    #pragma unroll
    for (int j = 0; j < 8; ++j) {
        int k = ks * 32 + kg * 8 + j;
        float wv = W[k * 256 + n];
        u16 h = f2bf(wv);
        hi[j] = h;
        lo[j] = f2bf(wv - bf2f(h));
    }
    *(u16x8*)&wsHi[(size_t)gid * 8] = *(u16x8*)hi;
    *(u16x8*)&wsLo[(size_t)gid * 8] = *(u16x8*)lo;
}

// ---------------- main fused kernel ----------------
// Block: 16 points, 4 waves. 7 LDS "planes" [16 pts][256 feats] bf16, XOR-swizzled:
//   byte(plane,m,k) = plane*8192 + m*512 + ((2k) ^ ((m&15)<<4))
// planes: 0=v_hi 1=v_lo 2=t_hi 3=t_lo 4=x 5=y 6=lap
// Per hidden layer, per (nt,ks): 9 MFMA (value 3-pass, t 3-pass, x/y/lap 1-pass).
// C layout (validated R2): row=n-in-tile=(lane>>4)*4+r, col=point=lane&15.

#define KSTEP(KS, WHC, WLC, WHN, WLN)                                                          \
  {                                                                                            \
    int ksn = ((KS) < 7) ? (KS) + 1 : 7;                                                       \
    size_t wb = ((size_t)(((L * 8 + ksn) * 16 + wv * 4) * 64 + lane)) * 8;                     \
    _Pragma("unroll")                                                                          \
    for (int nt = 0; nt < 4; ++nt) {                                                           \
      WHN[nt] = *(const bf16x8*)&wsHi[wb + nt * 512];                                          \
      WLN[nt] = *(const bf16x8*)&wsLo[wb + nt * 512];                                          \
    }                                                                                          \
    int hoff = mrow * 512 + ((64 * (KS) + 16 * kg) ^ (mrow << 4));                             \
    bf16x8 hvh = *(const bf16x8*)(Hb + 0 * 8192 + hoff);                                       \
    bf16x8 hvl = *(const bf16x8*)(Hb + 1 * 8192 + hoff);                                       \
    bf16x8 hth = *(const bf16x8*)(Hb + 2 * 8192 + hoff);                                       \
    bf16x8 htl = *(const bf16x8*)(Hb + 3 * 8192 + hoff);                                       \
    bf16x8 hx  = *(const bf16x8*)(Hb + 4 * 8192 + hoff);                                       \
    bf16x8 hy  = *(const bf16x8*)(Hb + 5 * 8192 + hoff);                                       \
    bf16x8 hlp = *(const bf16x8*)(Hb + 6 * 8192 + hoff);                                       \
    _Pragma("unroll")                                                                          \
    for (int nt = 0; nt < 4; ++nt) {                                                           \
      acc[0][nt] = __builtin_amdgcn_mfma_f32_16x16x32_bf16(WHC[nt], hvh, acc[0][nt], 0, 0, 0); \
      acc[0][nt] = __builtin_amdgcn_mfma_f32_16x16x32_bf16(WLC[nt], hvh, acc[0][nt], 0, 0, 0); \
      acc[0][nt] = __builtin_amdgcn_mfma_f32_16x16x32_bf16(WHC[nt], hvl, acc[0][nt], 0, 0, 0); \
      acc[1][nt] = __builtin_amdgcn_mfma_f32_16x16x32_bf16(WHC[nt], hth, acc[1][nt], 0, 0, 0); \
      acc[1][nt] = __builtin_amdgcn_mfma_f32_16x16x32_bf16(WLC[nt], hth, acc[1][nt], 0, 0, 0); \
      acc[1][nt] = __builtin_amdgcn_mfma_f32_16x16x32_bf16(WHC[nt], htl, acc[1][nt], 0, 0, 0); \
      acc[2][nt] = __builtin_amdgcn_mfma_f32_16x16x32_bf16(WHC[nt], hx,  acc[2][nt], 0, 0, 0); \
      acc[3][nt] = __builtin_amdgcn_mfma_f32_16x16x32_bf16(WHC[nt], hy,  acc[3][nt], 0, 0, 0); \
      acc[4][nt] = __builtin_amdgcn_mfma_f32_16x16x32_bf16(WHC[nt], hlp, acc[4][nt], 0, 0, 0); \
    }                                                                                          \
  }

__global__ __launch_bounds__(256, 2)
void pinn_mfma2(const float* __restrict__ t_in, const float* __restrict__ x_in,
                const float* __restrict__ y_in,
                const float* __restrict__ W0, const float* __restrict__ b0,
                const float* __restrict__ b1, const float* __restrict__ b2,
                const float* __restrict__ b3,
                const float* __restrict__ W4, const float* __restrict__ b4,
                const u16* __restrict__ wsHi, const u16* __restrict__ wsLo,
                float* __restrict__ out)
{
    __shared__ u16 H[7 * 16 * 256];    // 57344 B
    char* Hb = (char*)H;

    const int tid  = threadIdx.x;
    const int lane = tid & 63;
    const int wv   = tid >> 6;

    // ---- layer 0: 3 -> 256 ----
    {
        int p = tid & 15, c = tid >> 4;
        int g0 = blockIdx.x * 16 + p;
        float tv = t_in[g0], xv = x_in[g0], yv = y_in[g0];
        #pragma unroll
        for (int half = 0; half < 2; ++half) {
            int n0 = c * 16 + half * 8;
            float w0[8], w1[8], w2[8], bb[8];
            #pragma unroll
            for (int q = 0; q < 2; ++q) {
                *(float4*)&w0[q*4] = *(const float4*)&W0[0*256 + n0 + q*4];
                *(float4*)&w1[q*4] = *(const float4*)&W0[1*256 + n0 + q*4];
                *(float4*)&w2[q*4] = *(const float4*)&W0[2*256 + n0 + q*4];
                *(float4*)&bb[q*4] = *(const float4*)&b0[n0 + q*4];
            }
            u16 vh[8], vl[8], th[8], tl[8], xh[8], yh[8], lh[8];
            #pragma unroll
            for (int j = 0; j < 8; ++j) {
                float z = tv*w0[j] + xv*w1[j] + yv*w2[j] + bb[j];
                float a = tanh_fast(z);
                float g = 1.f - a*a;
                float ot = g * w0[j];
                float ox = g * w1[j];
                float oy = g * w2[j];
                float ol = -2.f * a * g * (w1[j]*w1[j] + w2[j]*w2[j]);
                vh[j] = f2bf(a);  vl[j] = f2bf(a  - bf2f(vh[j]));
                th[j] = f2bf(ot); tl[j] = f2bf(ot - bf2f(th[j]));
                xh[j] = f2bf(ox); yh[j] = f2bf(oy); lh[j] = f2bf(ol);
            }
            int off = p * 512 + ((c * 32 + half * 16) ^ (p << 4));
            *(u16x8*)(Hb + 0*8192 + off) = *(u16x8*)vh;
            *(u16x8*)(Hb + 1*8192 + off) = *(u16x8*)vl;
            *(u16x8*)(Hb + 2*8192 + off) = *(u16x8*)th;
            *(u16x8*)(Hb + 3*8192 + off) = *(u16x8*)tl;
            *(u16x8*)(Hb + 4*8192 + off) = *(u16x8*)xh;
            *(u16x8*)(Hb + 5*8192 + off) = *(u16x8*)yh;
            *(u16x8*)(Hb + 6*8192 + off) = *(u16x8*)lh;
        }
    }
    __syncthreads();

    const int mrow = lane & 15;   // point (B-frag row / C col)
    const int kg   = lane >> 4;   // k-group / C row-group

    #pragma unroll 1
    for (int L = 0; L < 3; ++L) {
        const float* bL = (L == 0) ? b1 : ((L == 1) ? b2 : b3);

        f32x4 acc[5][4];
        #pragma unroll
        for (int s = 0; s < 5; ++s)
            #pragma unroll
            for (int nt = 0; nt < 4; ++nt)
                acc[s][nt] = (f32x4){0.f, 0.f, 0.f, 0.f};

        bf16x8 whA[4], wlA[4], whB[4], wlB[4];
        {
            size_t wb0 = ((size_t)(((L * 8 + 0) * 16 + wv * 4) * 64 + lane)) * 8;
            #pragma unroll
            for (int nt = 0; nt < 4; ++nt) {
                whA[nt] = *(const bf16x8*)&wsHi[wb0 + nt * 512];
                wlA[nt] = *(const bf16x8*)&wsLo[wb0 + nt * 512];
            }
        }

        #pragma unroll 1
        for (int kso = 0; kso < 4; ++kso) {
            KSTEP(2 * kso,     whA, wlA, whB, wlB);
            KSTEP(2 * kso + 1, whB, wlB, whA, wlA);
        }
        __syncthreads();   // all H reads of this layer done

        // ---- coupling + write next-layer H ----
        #pragma unroll
        for (int nt = 0; nt < 4; ++nt) {
            int nb = (wv * 4 + nt) * 16 + kg * 4;
            float4 bv = *(const float4*)&bL[nb];
            float bva[4] = {bv.x, bv.y, bv.z, bv.w};
            u16 vh4[4], vl4[4], th4[4], tl4[4], xh4[4], yh4[4], lh4[4];
            #pragma unroll
            for (int r = 0; r < 4; ++r) {
                float z0 = acc[0][nt][r] + bva[r];
                float a  = tanh_fast(z0);
                float g  = 1.f - a * a;
                float zt = acc[1][nt][r];
                float zx = acc[2][nt][r];
                float zy = acc[3][nt][r];
                float zl = acc[4][nt][r];
                float ot = g * zt;
                float ox = g * zx;
                float oy = g * zy;
                float ol = g * zl - 2.f * a * g * (zx*zx + zy*zy);
                vh4[r] = f2bf(a);  vl4[r] = f2bf(a  - bf2f(vh4[r]));
                th4[r] = f2bf(ot); tl4[r] = f2bf(ot - bf2f(th4[r]));
                xh4[r] = f2bf(ox); yh4[r] = f2bf(oy); lh4[r] = f2bf(ol);
            }
            int off = mrow * 512 + ((2 * nb) ^ (mrow << 4));
            *(u16x4*)(Hb + 0*8192 + off) = *(u16x4*)vh4;
            *(u16x4*)(Hb + 1*8192 + off) = *(u16x4*)vl4;
            *(u16x4*)(Hb + 2*8192 + off) = *(u16x4*)th4;
            *(u16x4*)(Hb + 3*8192 + off) = *(u16x4*)tl4;
            *(u16x4*)(Hb + 4*8192 + off) = *(u16x4*)xh4;
            *(u16x4*)(Hb + 5*8192 + off) = *(u16x4*)yh4;
            *(u16x4*)(Hb + 6*8192 + off) = *(u16x4*)lh4;
        }
        __syncthreads();
    }

    // ---- final layer: 256 -> 2 (linear) + PDE residuals ----
    {
        int p = tid >> 4, i = tid & 15;
        float pu = 0.f, pv = 0.f, put = 0.f, pvt = 0.f, plu = 0.f, plv = 0.f;
        #pragma unroll
        for (int half = 0; half < 2; ++half) {
            int k0  = i * 16 + half * 8;
            int off = p * 512 + ((i * 32 + half * 16) ^ (p << 4));
            u16x8 vh = *(const u16x8*)(Hb + 0*8192 + off);
            u16x8 vl = *(const u16x8*)(Hb + 1*8192 + off);
            u16x8 th = *(const u16x8*)(Hb + 2*8192 + off);
            u16x8 tl = *(const u16x8*)(Hb + 3*8192 + off);
            u16x8 lp = *(const u16x8*)(Hb + 6*8192 + off);
            float w4[16];
            #pragma unroll
            for (int q = 0; q < 4; ++q)
                *(float4*)&w4[q*4] = *(const float4*)&W4[k0 * 2 + q * 4];
            #pragma unroll
            for (int j = 0; j < 8; ++j) {
                float vv = bf2f(vh[j]) + bf2f(vl[j]);
                float tt = bf2f(th[j]) + bf2f(tl[j]);
                float ll = bf2f(lp[j]);
                float wa = w4[2*j], wb2 = w4[2*j + 1];
                pu  += vv * wa;  pv  += vv * wb2;
                put += tt * wa;  pvt += tt * wb2;
                plu += ll * wa;  plv += ll * wb2;
            }
        }
        #pragma unroll
        for (int m = 1; m < 16; m <<= 1) {
            pu  += __shfl_xor(pu, m);   pv  += __shfl_xor(pv, m);
            put += __shfl_xor(put, m);  pvt += __shfl_xor(pvt, m);
            plu += __shfl_xor(plu, m);  plv += __shfl_xor(plv, m);
        }
        if (i == 0) {
            float u = pu + b4[0];
            float v = pv + b4[1];
            int gpt = blockIdx.x * 16 + p;
            float fo = u - u*u*u - K_CONST - v + D_U * plu - put;
            float go = u - v + D_V * plv - pvt;
            out[0 * N_PTS + gpt] = u;
            out[1 * N_PTS + gpt] = v;
            out[2 * N_PTS + gpt] = fo;
            out[3 * N_PTS + gpt] = go;
        }
    }
}

// ---------------- fallback (round-1 fp32 kernel) if ws too small ----------------
#define PTS   16
#define NTHR  256
#define HDIM  256
#define KC    32
#define HPAD  260

__global__ __launch_bounds__(NTHR, 1)
void pinn_diffreact_f32(const float* __restrict__ t_in, const float* __restrict__ x_in,
                        const float* __restrict__ y_in,
                        const float* __restrict__ W0, const float* __restrict__ b0,
                        const float* __restrict__ W1, const float* __restrict__ b1,
                        const float* __restrict__ W2, const float* __restrict__ b2,
                        const float* __restrict__ W3, const float* __restrict__ b3,
                        const float* __restrict__ W4, const float* __restrict__ b4,
                        float* __restrict__ out)
{
    __shared__ float Hs[6 * PTS * HPAD];
    __shared__ float Wc[KC * HDIM];
    const int tid = threadIdx.x;
    const int pt = tid >> 4;
    const int fbase = (tid & 15) * 4;
    const int gpt = blockIdx.x * PTS + pt;
    {
        const float tv = t_in[gpt], xv = x_in[gpt], yv = y_in[gpt];
        #pragma unroll
        for (int jv = 0; jv < 4; ++jv)
            #pragma unroll
            for (int q = 0; q < 4; ++q) {
                const int f = fbase + jv * 64 + q;
                const float w0 = W0[f], w1 = W0[256 + f], w2 = W0[512 + f];
                const float z = tv*w0 + xv*w1 + yv*w2 + b0[f];
                const float a = tanhf(z), g = 1.f - a*a;
                Hs[(0*PTS+pt)*HPAD+f] = a;
                Hs[(1*PTS+pt)*HPAD+f] = g*w0;
                Hs[(2*PTS+pt)*HPAD+f] = g*w1;
                Hs[(3*PTS+pt)*HPAD+f] = g*w2;
                Hs[(4*PTS+pt)*HPAD+f] = -2.f*a*g*w1*w1;
                Hs[(5*PTS+pt)*HPAD+f] = -2.f*a*g*w2*w2;
            }
    }
    __syncthreads();
    const float* Ws[3] = {W1, W2, W3};
    const float* bs[3] = {b1, b2, b3};
    for (int L = 0; L < 3; ++L) {
        const float* __restrict__ W = Ws[L];
        const float* __restrict__ b = bs[L];
        float acc[6][16];
        #pragma unroll
        for (int s = 0; s < 6; ++s)
            #pragma unroll
            for (int j = 0; j < 16; ++j) acc[s][j] = 0.f;
        for (int kc = 0; kc < HDIM / KC; ++kc) {
            __syncthreads();
            const float4* src = (const float4*)(W + kc * KC * HDIM);
            float4* dst = (float4*)Wc;
            #pragma unroll
            for (int i2 = 0; i2 < (KC * HDIM / 4) / NTHR; ++i2)
                dst[tid + i2 * NTHR] = src[tid + i2 * NTHR];
            __syncthreads();
            #pragma unroll
            for (int k4 = 0; k4 < KC; k4 += 4) {
                float4 h[6];
                #pragma unroll
                for (int s = 0; s < 6; ++s)
                    h[s] = *(const float4*)&Hs[(s*PTS+pt)*HPAD + kc*KC + k4];
                #pragma unroll
                for (int q = 0; q < 4; ++q) {
                    float hv[6];
                    #pragma unroll
                    for (int s = 0; s < 6; ++s)
                        hv[s] = (q==0) ? h[s].x : (q==1) ? h[s].y : (q==2) ? h[s].z : h[s].w;
                    #pragma unroll
                    for (int jv = 0; jv < 4; ++jv) {
                        const float4 wq = *(const float4*)&Wc[(k4+q)*HDIM + fbase + jv*64];
                        const float wvv[4] = {wq.x, wq.y, wq.z, wq.w};
                        #pragma unroll
                        for (int r = 0; r < 4; ++r)
                            #pragma unroll
                            for (int s = 0; s < 6; ++s)
                                acc[s][jv*4+r] += hv[s] * wvv[r];
                    }
                }
            }
        }
        __syncthreads();
        #pragma unroll
        for (int jv = 0; jv < 4; ++jv)
            #pragma unroll
            for (int q = 0; q < 4; ++q) {
                const int j = jv*4+q, f = fbase + jv*64 + q;
                const float z = acc[0][j] + b[f];
                const float a = tanhf(z), g = 1.f - a*a;
                const float zt = acc[1][j], zx = acc[2][j], zy = acc[3][j];
                const float zxx = acc[4][j], zyy = acc[5][j];
                Hs[(0*PTS+pt)*HPAD+f] = a;
                Hs[(1*PTS+pt)*HPAD+f] = g*zt;
                Hs[(2*PTS+pt)*HPAD+f] = g*zx;
                Hs[(3*PTS+pt)*HPAD+f] = g*zy;
                Hs[(4*PTS+pt)*HPAD+f] = g*zxx - 2.f*a*g*zx*zx;
                Hs[(5*PTS+pt)*HPAD+f] = g*zyy - 2.f*a*g*zy*zy;
            }
        __syncthreads();
    }
    float p[6][2];
    #pragma unroll
    for (int s = 0; s < 6; ++s) { p[s][0] = 0.f; p[s][1] = 0.f; }
    #pragma unroll
    for (int jv = 0; jv < 4; ++jv)
        #pragma unroll
        for (int q = 0; q < 4; ++q) {
            const int f = fbase + jv*64 + q;
            const float w0 = W4[f*2], w1 = W4[f*2+1];
            #pragma unroll
            for (int s = 0; s < 6; ++s) {
                const float hv = Hs[(s*PTS+pt)*HPAD+f];
                p[s][0] += hv*w0; p[s][1] += hv*w1;
            }
        }
    #pragma unroll
    for (int m = 1; m < 16; m <<= 1)
        #pragma unroll
        for (int s = 0; s < 6; ++s) {
            p[s][0] += __shfl_xor(p[s][0], m);
            p[s][1] += __shfl_xor(p[s][1], m);
        }
    if ((tid & 15) == 0) {
        const float u = p[0][0] + b4[0];
        const float v = p[0][1] + b4[1];
        const float ut = p[1][0], vt = p[1][1];
        const float uxx = p[4][0], vxx = p[4][1];
        const float uyy = p[5][0], vyy = p[5][1];
        const float fo = u - u*u*u - K_CONST - v + D_U*(uxx+uyy) - ut;
        const float go = u - v + D_V*(vxx+vyy) - vt;
        out[0*N_PTS+gpt] = u;
        out[1*N_PTS+gpt] = v;
        out[2*N_PTS+gpt] = fo;
        out[3*N_PTS+gpt] = go;
    }
}

extern "C" void kernel_launch(void* const* d_in, const int* in_sizes, int n_in,
                              void* d_out, int out_size, void* d_ws, size_t ws_size,
                              hipStream_t stream)
{
    const float* t_in = (const float*)d_in[0];
    const float* x_in = (const float*)d_in[1];
    const float* y_in = (const float*)d_in[2];
    const float* W0 = (const float*)d_in[3];
    const float* b0 = (const float*)d_in[4];
    const float* W1 = (const float*)d_in[5];
    const float* b1 = (const float*)d_in[6];
    const float* W2 = (const float*)d_in[7];
    const float* b2 = (const float*)d_in[8];
    const float* W3 = (const float*)d_in[9];
    const float* b3 = (const float*)d_in[10];
    const float* W4 = (const float*)d_in[11];
    const float* b4 = (const float*)d_in[12];
    float* out = (float*)d_out;

    const size_t WS_NEEDED = (size_t)3 * 8 * 16 * 64 * 8 * 2 * 2;  // 786432 B
    if (ws_size >= WS_NEEDED) {
        u16* wsHi = (u16*)d_ws;
        u16* wsLo = wsHi + 196608;
        hipLaunchKernelGGL(prep_weights, dim3(96), dim3(256), 0, stream, W1, W2, W3, wsHi, wsLo);
        hipLaunchKernelGGL(pinn_mfma2, dim3(N_PTS / 16), dim3(256), 0, stream,
                           t_in, x_in, y_in, W0, b0, b1, b2, b3, W4, b4, wsHi, wsLo, out);
    } else {
        hipLaunchKernelGGL(pinn_diffreact_f32, dim3(N_PTS / PTS), dim3(NTHR), 0, stream,
                           t_in, x_in, y_in, W0, b0, W1, b1, W2, b2, W3, b3, W4, b4, out);
    }
}

// Round 4
// 436.761 us; speedup vs baseline: 10.3422x; 1.1147x over previous
//
#include <hip/hip_runtime.h>
#include <math.h>

#define N_PTS   131072
#define K_CONST 0.005f
#define D_U     0.001f
#define D_V     0.005f

typedef unsigned short u16;
typedef __attribute__((ext_vector_type(8))) short  bf16x8;
typedef __attribute__((ext_vector_type(4))) float  f32x4;
typedef __attribute__((ext_vector_type(4))) u16    u16x4;
typedef __attribute__((ext_vector_type(8))) u16    u16x8;

// Native bf16 convert (gfx950: v_cvt_pk_bf16_f32, RNE) — per m240, plain casts
// beat hand-written cvt asm. Manual fallback is bit-identical (both RNE).
__device__ __forceinline__ u16 f2bf(float x){
    __bf16 b = (__bf16)x;
    return __builtin_bit_cast(u16, b);
}
__device__ __forceinline__ float bf2f(u16 h){ return __uint_as_float(((unsigned)h) << 16); }

__device__ __forceinline__ float tanh_fast(float z){
    float e = __expf(2.f * z);
    return 1.f - 2.f * __builtin_amdgcn_rcpf(e + 1.f);
}

// ---------------- prep: split W1..W3 into bf16 hi/lo, W^T fragment layout ----------------
// layout: idx = (((L*8 + ks)*16 + ntg)*64 + lane)*8 + j
// value  = W[k][n], k = ks*32 + (lane>>4)*8 + j, n = ntg*16 + (lane&15)
__global__ void prep_weights(const float* __restrict__ W1, const float* __restrict__ W2,
                             const float* __restrict__ W3,
                             u16* __restrict__ wsHi, u16* __restrict__ wsLo)
{
    int gid  = blockIdx.x * 256 + threadIdx.x;   // 0 .. 24575
    int lane = gid & 63;
    int nt   = (gid >> 6) & 15;
    int ks   = (gid >> 10) & 7;
    int L    = gid >> 13;
    if (L >= 3) return;
    const float* W = (L == 0) ? W1 : ((L == 1) ? W2 : W3);
    int n  = nt * 16 + (lane & 15);
    int kg = lane >> 4;
    u16 hi[8], lo[8];
    #pragma unroll
    for (int j = 0; j < 8; ++j) {
        int k = ks * 32 + kg * 8 + j;
        float wv = W[k * 256 + n];
        u16 h = f2bf(wv);
        hi[j] = h;
        lo[j] = f2bf(wv - bf2f(h));
    }
    *(u16x8*)&wsHi[(size_t)gid * 8] = *(u16x8*)hi;
    *(u16x8*)&wsLo[(size_t)gid * 8] = *(u16x8*)lo;
}

// ---------------- main fused kernel ----------------
// Block: 16 points, 4 waves. 7 LDS planes [16 pts][256 feats] bf16, XOR-swizzled:
//   byte(plane,m,k) = plane*8192 + m*512 + ((2k) ^ ((m&15)<<4))
// planes: 0=v_hi 1=v_lo 2=t_hi 3=t_lo 4=x 5=y 6=lap
// Per (nt,ks): 9 MFMA (value 3-pass, t 3-pass, x/y/lap 1-pass).
// C layout: row = n-in-tile = (lane>>4)*4+r, col = point = lane&15.

#define KSTEP(KS, WHC, WLC, WHN, WLN, PNH, PNL)                                                \
  {                                                                                            \
    _Pragma("unroll")                                                                          \
    for (int nt = 0; nt < 4; ++nt) {                                                           \
      WHN[nt] = *(const bf16x8*)((PNH) + nt * 512);                                            \
      WLN[nt] = *(const bf16x8*)((PNL) + nt * 512);                                            \
    }                                                                                          \
    int hoff = mbase + ((64 * (KS) + 16 * kg) ^ mxor);                                         \
    bf16x8 hvh = *(const bf16x8*)(Hb + 0 * 8192 + hoff);                                       \
    bf16x8 hvl = *(const bf16x8*)(Hb + 1 * 8192 + hoff);                                       \
    bf16x8 hth = *(const bf16x8*)(Hb + 2 * 8192 + hoff);                                       \
    bf16x8 htl = *(const bf16x8*)(Hb + 3 * 8192 + hoff);                                       \
    bf16x8 hx  = *(const bf16x8*)(Hb + 4 * 8192 + hoff);                                       \
    bf16x8 hy  = *(const bf16x8*)(Hb + 5 * 8192 + hoff);                                       \
    bf16x8 hlp = *(const bf16x8*)(Hb + 6 * 8192 + hoff);                                       \
    __builtin_amdgcn_s_setprio(1);                                                             \
    _Pragma("unroll")                                                                          \
    for (int nt = 0; nt < 4; ++nt) {                                                           \
      acc[0][nt] = __builtin_amdgcn_mfma_f32_16x16x32_bf16(WHC[nt], hvh, acc[0][nt], 0, 0, 0); \
      acc[0][nt] = __builtin_amdgcn_mfma_f32_16x16x32_bf16(WLC[nt], hvh, acc[0][nt], 0, 0, 0); \
      acc[0][nt] = __builtin_amdgcn_mfma_f32_16x16x32_bf16(WHC[nt], hvl, acc[0][nt], 0, 0, 0); \
      acc[1][nt] = __builtin_amdgcn_mfma_f32_16x16x32_bf16(WHC[nt], hth, acc[1][nt], 0, 0, 0); \
      acc[1][nt] = __builtin_amdgcn_mfma_f32_16x16x32_bf16(WLC[nt], hth, acc[1][nt], 0, 0, 0); \
      acc[1][nt] = __builtin_amdgcn_mfma_f32_16x16x32_bf16(WHC[nt], htl, acc[1][nt], 0, 0, 0); \
      acc[2][nt] = __builtin_amdgcn_mfma_f32_16x16x32_bf16(WHC[nt], hx,  acc[2][nt], 0, 0, 0); \
      acc[3][nt] = __builtin_amdgcn_mfma_f32_16x16x32_bf16(WHC[nt], hy,  acc[3][nt], 0, 0, 0); \
      acc[4][nt] = __builtin_amdgcn_mfma_f32_16x16x32_bf16(WHC[nt], hlp, acc[4][nt], 0, 0, 0); \
    }                                                                                          \
    __builtin_amdgcn_s_setprio(0);                                                             \
  }

__global__ __launch_bounds__(256, 2)
void pinn_mfma3(const float* __restrict__ t_in, const float* __restrict__ x_in,
                const float* __restrict__ y_in,
                const float* __restrict__ W0, const float* __restrict__ b0,
                const float* __restrict__ b1, const float* __restrict__ b2,
                const float* __restrict__ b3,
                const float* __restrict__ W4, const float* __restrict__ b4,
                const u16* __restrict__ wsHi, const u16* __restrict__ wsLo,
                float* __restrict__ out)
{
    __shared__ u16 H[7 * 16 * 256];    // 57344 B
    char* Hb = (char*)H;

    const int tid  = threadIdx.x;
    const int lane = tid & 63;
    const int wv   = tid >> 6;

    // ---- layer 0: 3 -> 256 ----
    {
        int p = tid & 15, c = tid >> 4;
        int g0 = blockIdx.x * 16 + p;
        float tv = t_in[g0], xv = x_in[g0], yv = y_in[g0];
        #pragma unroll
        for (int half = 0; half < 2; ++half) {
            int n0 = c * 16 + half * 8;
            float w0[8], w1[8], w2[8], bb[8];
            #pragma unroll
            for (int q = 0; q < 2; ++q) {
                *(float4*)&w0[q*4] = *(const float4*)&W0[0*256 + n0 + q*4];
                *(float4*)&w1[q*4] = *(const float4*)&W0[1*256 + n0 + q*4];
                *(float4*)&w2[q*4] = *(const float4*)&W0[2*256 + n0 + q*4];
                *(float4*)&bb[q*4] = *(const float4*)&b0[n0 + q*4];
            }
            u16 vh[8], vl[8], th[8], tl[8], xh[8], yh[8], lh[8];
            #pragma unroll
            for (int j = 0; j < 8; ++j) {
                float z = tv*w0[j] + xv*w1[j] + yv*w2[j] + bb[j];
                float a = tanh_fast(z);
                float g = 1.f - a*a;
                float ot = g * w0[j];
                float ox = g * w1[j];
                float oy = g * w2[j];
                float ol = -2.f * a * g * (w1[j]*w1[j] + w2[j]*w2[j]);
                vh[j] = f2bf(a);  vl[j] = f2bf(a  - bf2f(vh[j]));
                th[j] = f2bf(ot); tl[j] = f2bf(ot - bf2f(th[j]));
                xh[j] = f2bf(ox); yh[j] = f2bf(oy); lh[j] = f2bf(ol);
            }
            int off = p * 512 + ((c * 32 + half * 16) ^ (p << 4));
            *(u16x8*)(Hb + 0*8192 + off) = *(u16x8*)vh;
            *(u16x8*)(Hb + 1*8192 + off) = *(u16x8*)vl;
            *(u16x8*)(Hb + 2*8192 + off) = *(u16x8*)th;
            *(u16x8*)(Hb + 3*8192 + off) = *(u16x8*)tl;
            *(u16x8*)(Hb + 4*8192 + off) = *(u16x8*)xh;
            *(u16x8*)(Hb + 5*8192 + off) = *(u16x8*)yh;
            *(u16x8*)(Hb + 6*8192 + off) = *(u16x8*)lh;
        }
    }
    __syncthreads();

    const int mrow  = lane & 15;        // point (B-frag row / C col)
    const int kg    = lane >> 4;        // k-group / C row-group
    const int mxor  = mrow << 4;
    const int mbase = mrow * 512;

    // per-thread weight-fragment base pointers (pointer-bump addressing)
    const u16* pWbh = wsHi + wv * 2048 + lane * 8;
    const u16* pWbl = wsLo + wv * 2048 + lane * 8;

    bf16x8 whA[4], wlA[4], whB[4], wlB[4];
    {   // initial load: L=0, ks=0
        #pragma unroll
        for (int nt = 0; nt < 4; ++nt) {
            whA[nt] = *(const bf16x8*)(pWbh + nt * 512);
            wlA[nt] = *(const bf16x8*)(pWbl + nt * 512);
        }
    }

    #pragma unroll 1
    for (int L = 0; L < 3; ++L) {
        const float* bL = (L == 0) ? b1 : ((L == 1) ? b2 : b3);

        // hoist bias (latency hidden under MFMA loop)
        float4 bv4[4];
        #pragma unroll
        for (int nt = 0; nt < 4; ++nt)
            bv4[nt] = *(const float4*)&bL[(wv * 4 + nt) * 16 + kg * 4];

        f32x4 acc[5][4];
        #pragma unroll
        for (int s = 0; s < 5; ++s)
            #pragma unroll
            for (int nt = 0; nt < 4; ++nt)
                acc[s][nt] = (f32x4){0.f, 0.f, 0.f, 0.f};

        const u16* pLh = pWbh + L * 65536;
        const u16* pLl = pWbl + L * 65536;
        const int  Ln  = (L < 2) ? (L + 1) : 2;
        const u16* pNh = pWbh + Ln * 65536;
        const u16* pNl = pWbl + Ln * 65536;

        KSTEP(0, whA, wlA, whB, wlB, pLh + 1*8192, pLl + 1*8192);
        KSTEP(1, whB, wlB, whA, wlA, pLh + 2*8192, pLl + 2*8192);
        KSTEP(2, whA, wlA, whB, wlB, pLh + 3*8192, pLl + 3*8192);
        KSTEP(3, whB, wlB, whA, wlA, pLh + 4*8192, pLl + 4*8192);
        KSTEP(4, whA, wlA, whB, wlB, pLh + 5*8192, pLl + 5*8192);
        KSTEP(5, whB, wlB, whA, wlA, pLh + 6*8192, pLl + 6*8192);
        KSTEP(6, whA, wlA, whB, wlB, pLh + 7*8192, pLl + 7*8192);
        KSTEP(7, whB, wlB, whA, wlA, pNh, pNl);   // prefetch next layer ks=0

        __syncthreads();   // all H reads of this layer done

        // ---- coupling + write next-layer H ----
        #pragma unroll
        for (int nt = 0; nt < 4; ++nt) {
            int nb = (wv * 4 + nt) * 16 + kg * 4;
            float bva[4] = {bv4[nt].x, bv4[nt].y, bv4[nt].z, bv4[nt].w};
            u16 vh4[4], vl4[4], th4[4], tl4[4], xh4[4], yh4[4], lh4[4];
            #pragma unroll
            for (int r = 0; r < 4; ++r) {
                float z0 = acc[0][nt][r] + bva[r];
                float a  = tanh_fast(z0);
                float g  = 1.f - a * a;
                float zt = acc[1][nt][r];
                float zx = acc[2][nt][r];
                float zy = acc[3][nt][r];
                float zl = acc[4][nt][r];
                float ot = g * zt;
                float ox = g * zx;
                float oy = g * zy;
                float ol = g * zl - 2.f * a * g * (zx*zx + zy*zy);
                vh4[r] = f2bf(a);  vl4[r] = f2bf(a  - bf2f(vh4[r]));
                th4[r] = f2bf(ot); tl4[r] = f2bf(ot - bf2f(th4[r]));
                xh4[r] = f2bf(ox); yh4[r] = f2bf(oy); lh4[r] = f2bf(ol);
            }
            int off = mbase + ((2 * nb) ^ mxor);
            *(u16x4*)(Hb + 0*8192 + off) = *(u16x4*)vh4;
            *(u16x4*)(Hb + 1*8192 + off) = *(u16x4*)vl4;
            *(u16x4*)(Hb + 2*8192 + off) = *(u16x4*)th4;
            *(u16x4*)(Hb + 3*8192 + off) = *(u16x4*)tl4;
            *(u16x4*)(Hb + 4*8192 + off) = *(u16x4*)xh4;
            *(u16x4*)(Hb + 5*8192 + off) = *(u16x4*)yh4;
            *(u16x4*)(Hb + 6*8192 + off) = *(u16x4*)lh4;
        }
        __syncthreads();
    }

    // ---- final layer: 256 -> 2 (linear) + PDE residuals ----
    {
        int p = tid >> 4, i = tid & 15;
        float pu = 0.f, pv = 0.f, put = 0.f, pvt = 0.f, plu = 0.f, plv = 0.f;
        #pragma unroll
        for (int half = 0; half < 2; ++half) {
            int k0  = i * 16 + half * 8;
            int off = p * 512 + ((i * 32 + half * 16) ^ (p << 4));
            u16x8 vh = *(const u16x8*)(Hb + 0*8192 + off);
            u16x8 vl = *(const u16x8*)(Hb + 1*8192 + off);
            u16x8 th = *(const u16x8*)(Hb + 2*8192 + off);
            u16x8 tl = *(const u16x8*)(Hb + 3*8192 + off);
            u16x8 lp = *(const u16x8*)(Hb + 6*8192 + off);
            float w4[16];
            #pragma unroll
            for (int q = 0; q < 4; ++q)
                *(float4*)&w4[q*4] = *(const float4*)&W4[k0 * 2 + q * 4];
            #pragma unroll
            for (int j = 0; j < 8; ++j) {
                float vv = bf2f(vh[j]) + bf2f(vl[j]);
                float tt = bf2f(th[j]) + bf2f(tl[j]);
                float ll = bf2f(lp[j]);
                float wa = w4[2*j], wb2 = w4[2*j + 1];
                pu  += vv * wa;  pv  += vv * wb2;
                put += tt * wa;  pvt += tt * wb2;
                plu += ll * wa;  plv += ll * wb2;
            }
        }
        // reduce across the 16 lanes (i = tid&15) sharing this point: masks 1,2,4,8
        #pragma unroll
        for (int m = 1; m < 16; m <<= 1) {
            pu  += __shfl_xor(pu, m);   pv  += __shfl_xor(pv, m);
            put += __shfl_xor(put, m);  pvt += __shfl_xor(pvt, m);
            plu += __shfl_xor(plu, m);  plv += __shfl_xor(plv, m);
        }
        if (i == 0) {
            float u = pu + b4[0];
            float v = pv + b4[1];
            int gpt = blockIdx.x * 16 + p;
            float fo = u - u*u*u - K_CONST - v + D_U * plu - put;
            float go = u - v + D_V * plv - pvt;
            out[0 * N_PTS + gpt] = u;
            out[1 * N_PTS + gpt] = v;
            out[2 * N_PTS + gpt] = fo;
            out[3 * N_PTS + gpt] = go;
        }
    }
}

// ---------------- fallback (round-1 fp32 kernel) if ws too small ----------------
#define PTS   16
#define NTHR  256
#define HDIM  256
#define KC    32
#define HPAD  260

__global__ __launch_bounds__(NTHR, 1)
void pinn_diffreact_f32(const float* __restrict__ t_in, const float* __restrict__ x_in,
                        const float* __restrict__ y_in,
                        const float* __restrict__ W0, const float* __restrict__ b0,
                        const float* __restrict__ W1, const float* __restrict__ b1,
                        const float* __restrict__ W2, const float* __restrict__ b2,
                        const float* __restrict__ W3, const float* __restrict__ b3,
                        const float* __restrict__ W4, const float* __restrict__ b4,
                        float* __restrict__ out)
{
    __shared__ float Hs[6 * PTS * HPAD];
    __shared__ float Wc[KC * HDIM];
    const int tid = threadIdx.x;
    const int pt = tid >> 4;
    const int fbase = (tid & 15) * 4;
    const int gpt = blockIdx.x * PTS + pt;
    {
        const float tv = t_in[gpt], xv = x_in[gpt], yv = y_in[gpt];
        #pragma unroll
        for (int jv = 0; jv < 4; ++jv)
            #pragma unroll
            for (int q = 0; q < 4; ++q) {
                const int f = fbase + jv * 64 + q;
                const float w0 = W0[f], w1 = W0[256 + f], w2 = W0[512 + f];
                const float z = tv*w0 + xv*w1 + yv*w2 + b0[f];
                const float a = tanhf(z), g = 1.f - a*a;
                Hs[(0*PTS+pt)*HPAD+f] = a;
                Hs[(1*PTS+pt)*HPAD+f] = g*w0;
                Hs[(2*PTS+pt)*HPAD+f] = g*w1;
                Hs[(3*PTS+pt)*HPAD+f] = g*w2;
                Hs[(4*PTS+pt)*HPAD+f] = -2.f*a*g*w1*w1;
                Hs[(5*PTS+pt)*HPAD+f] = -2.f*a*g*w2*w2;
            }
    }
    __syncthreads();
    const float* Ws[3] = {W1, W2, W3};
    const float* bs[3] = {b1, b2, b3};
    for (int L = 0; L < 3; ++L) {
        const float* __restrict__ W = Ws[L];
        const float* __restrict__ b = bs[L];
        float acc[6][16];
        #pragma unroll
        for (int s = 0; s < 6; ++s)
            #pragma unroll
            for (int j = 0; j < 16; ++j) acc[s][j] = 0.f;
        for (int kc = 0; kc < HDIM / KC; ++kc) {
            __syncthreads();
            const float4* src = (const float4*)(W + kc * KC * HDIM);
            float4* dst = (float4*)Wc;
            #pragma unroll
            for (int i2 = 0; i2 < (KC * HDIM / 4) / NTHR; ++i2)
                dst[tid + i2 * NTHR] = src[tid + i2 * NTHR];
            __syncthreads();
            #pragma unroll
            for (int k4 = 0; k4 < KC; k4 += 4) {
                float4 h[6];
                #pragma unroll
                for (int s = 0; s < 6; ++s)
                    h[s] = *(const float4*)&Hs[(s*PTS+pt)*HPAD + kc*KC + k4];
                #pragma unroll
                for (int q = 0; q < 4; ++q) {
                    float hv[6];
                    #pragma unroll
                    for (int s = 0; s < 6; ++s)
                        hv[s] = (q==0) ? h[s].x : (q==1) ? h[s].y : (q==2) ? h[s].z : h[s].w;
                    #pragma unroll
                    for (int jv = 0; jv < 4; ++jv) {
                        const float4 wq = *(const float4*)&Wc[(k4+q)*HDIM + fbase + jv*64];
                        const float wvv[4] = {wq.x, wq.y, wq.z, wq.w};
                        #pragma unroll
                        for (int r = 0; r < 4; ++r)
                            #pragma unroll
                            for (int s = 0; s < 6; ++s)
                                acc[s][jv*4+r] += hv[s] * wvv[r];
                    }
                }
            }
        }
        __syncthreads();
        #pragma unroll
        for (int jv = 0; jv < 4; ++jv)
            #pragma unroll
            for (int q = 0; q < 4; ++q) {
                const int j = jv*4+q, f = fbase + jv*64 + q;
                const float z = acc[0][j] + b[f];
                const float a = tanhf(z), g = 1.f - a*a;
                const float zt = acc[1][j], zx = acc[2][j], zy = acc[3][j];
                const float zxx = acc[4][j], zyy = acc[5][j];
                Hs[(0*PTS+pt)*HPAD+f] = a;
                Hs[(1*PTS+pt)*HPAD+f] = g*zt;
                Hs[(2*PTS+pt)*HPAD+f] = g*zx;
                Hs[(3*PTS+pt)*HPAD+f] = g*zy;
                Hs[(4*PTS+pt)*HPAD+f] = g*zxx - 2.f*a*g*zx*zx;
                Hs[(5*PTS+pt)*HPAD+f] = g*zyy - 2.f*a*g*zy*zy;
            }
        __syncthreads();
    }
    float p[6][2];
    #pragma unroll
    for (int s = 0; s < 6; ++s) { p[s][0] = 0.f; p[s][1] = 0.f; }
    #pragma unroll
    for (int jv = 0; jv < 4; ++jv)
        #pragma unroll
        for (int q = 0; q < 4; ++q) {
            const int f = fbase + jv*64 + q;
            const float w0 = W4[f*2], w1 = W4[f*2+1];
            #pragma unroll
            for (int s = 0; s < 6; ++s) {
                const float hv = Hs[(s*PTS+pt)*HPAD+f];
                p[s][0] += hv*w0; p[s][1] += hv*w1;
            }
        }
    #pragma unroll
    for (int m = 1; m < 16; m <<= 1)
        #pragma unroll
        for (int s = 0; s < 6; ++s) {
            p[s][0] += __shfl_xor(p[s][0], m);
            p[s][1] += __shfl_xor(p[s][1], m);
        }
    if ((tid & 15) == 0) {
        const float u = p[0][0] + b4[0];
        const float v = p[0][1] + b4[1];
        const float ut = p[1][0], vt = p[1][1];
        const float uxx = p[4][0], vxx = p[4][1];
        const float uyy = p[5][0], vyy = p[5][1];
        const float fo = u - u*u*u - K_CONST - v + D_U*(uxx+uyy) - ut;
        const float go = u - v + D_V*(vxx+vyy) - vt;
        out[0*N_PTS+gpt] = u;
        out[1*N_PTS+gpt] = v;
        out[2*N_PTS+gpt] = fo;
        out[3*N_PTS+gpt] = go;
    }
}

extern "C" void kernel_launch(void* const* d_in, const int* in_sizes, int n_in,
                              void* d_out, int out_size, void* d_ws, size_t ws_size,
                              hipStream_t stream)
{
    const float* t_in = (const float*)d_in[0];
    const float* x_in = (const float*)d_in[1];
    const float* y_in = (const float*)d_in[2];
    const float* W0 = (const float*)d_in[3];
    const float* b0 = (const float*)d_in[4];
    const float* W1 = (const float*)d_in[5];
    const float* b1 = (const float*)d_in[6];
    const float* W2 = (const float*)d_in[7];
    const float* b2 = (const float*)d_in[8];
    const float* W3 = (const float*)d_in[9];
    const float* b3 = (const float*)d_in[10];
    const float* W4 = (const float*)d_in[11];
    const float* b4 = (const float*)d_in[12];
    float* out = (float*)d_out;

    const size_t WS_NEEDED = (size_t)3 * 8 * 16 * 64 * 8 * 2 * 2;  // 786432 B
    if (ws_size >= WS_NEEDED) {
        u16* wsHi = (u16*)d_ws;
        u16* wsLo = wsHi + 196608;
        hipLaunchKernelGGL(prep_weights, dim3(96), dim3(256), 0, stream, W1, W2, W3, wsHi, wsLo);
        hipLaunchKernelGGL(pinn_mfma3, dim3(N_PTS / 16), dim3(256), 0, stream,
                           t_in, x_in, y_in, W0, b0, b1, b2, b3, W4, b4, wsHi, wsLo, out);
    } else {
        hipLaunchKernelGGL(pinn_diffreact_f32, dim3(N_PTS / PTS), dim3(NTHR), 0, stream,
                           t_in, x_in, y_in, W0, b0, W1, b1, W2, b2, W3, b3, W4, b4, out);
    }
}

// Round 5
// 353.621 us; speedup vs baseline: 12.7737x; 1.2351x over previous
//
#include <hip/hip_runtime.h>
#include <math.h>

#define N_PTS   131072
#define K_CONST 0.005f
#define D_U     0.001f
#define D_V     0.005f

typedef unsigned short u16;
typedef __attribute__((ext_vector_type(8))) _Float16 f16x8;
typedef __attribute__((ext_vector_type(4))) float    f32x4;
typedef __attribute__((ext_vector_type(4))) u16      u16x4;
typedef __attribute__((ext_vector_type(8))) u16      u16x8;

__device__ __forceinline__ u16 f2h(float x){
    _Float16 h = (_Float16)x;                 // v_cvt_f16_f32 (RNE)
    return __builtin_bit_cast(u16, h);
}
__device__ __forceinline__ float h2f(u16 h){
    return (float)__builtin_bit_cast(_Float16, h);
}

__device__ __forceinline__ float tanh_fast(float z){
    float e = __expf(2.f * z);
    return 1.f - 2.f * __builtin_amdgcn_rcpf(e + 1.f);
}

// ---------------- prep: W1..W3 -> fp16, W^T fragment layout ----------------
// idx = (((L*8 + ks)*16 + nt)*64 + lane)*8 + j
// val = W[k][n], k = ks*32 + (lane>>4)*8 + j, n = nt*16 + (lane&15)
__global__ void prep_weights(const float* __restrict__ W1, const float* __restrict__ W2,
                             const float* __restrict__ W3, u16* __restrict__ ws)
{
    int gid  = blockIdx.x * 256 + threadIdx.x;   // 0 .. 24575
    int lane = gid & 63;
    int nt   = (gid >> 6) & 15;
    int ks   = (gid >> 10) & 7;
    int L    = gid >> 13;
    if (L >= 3) return;
    const float* W = (L == 0) ? W1 : ((L == 1) ? W2 : W3);
    int n  = nt * 16 + (lane & 15);
    int kg = lane >> 4;
    u16 h[8];
    #pragma unroll
    for (int j = 0; j < 8; ++j) {
        int k = ks * 32 + kg * 8 + j;
        h[j] = f2h(W[k * 256 + n]);
    }
    *(u16x8*)&ws[(size_t)gid * 8] = *(u16x8*)h;
}

// ---------------- main fused kernel ----------------
// Block: 16 points, 4 waves. 5 LDS planes [16 pts][256 feats] fp16, XOR-swizzled:
//   byte(plane,m,k) = plane*8192 + m*512 + ((2k) ^ ((m&15)<<4))
// planes: 0=value 1=d/dt 2=d/dx 3=d/dy 4=laplacian
// Per (nt,ks): 5 MFMA (one per stream), fp16 single-pass.
// C layout: row = n-in-tile = (lane>>4)*4+r, col = point = lane&15.

#define KSTEP(KS, WC, WN, PN)                                                              \
  {                                                                                        \
    _Pragma("unroll")                                                                      \
    for (int nt = 0; nt < 4; ++nt)                                                         \
      WN[nt] = *(const f16x8*)((PN) + nt * 512);                                           \
    int hoff = mbase + ((64 * (KS) + 16 * kg) ^ mxor);                                     \
    f16x8 hv = *(const f16x8*)(Hb + 0 * 8192 + hoff);                                      \
    f16x8 ht = *(const f16x8*)(Hb + 1 * 8192 + hoff);                                      \
    f16x8 hx = *(const f16x8*)(Hb + 2 * 8192 + hoff);                                      \
    f16x8 hy = *(const f16x8*)(Hb + 3 * 8192 + hoff);                                      \
    f16x8 hl = *(const f16x8*)(Hb + 4 * 8192 + hoff);                                      \
    __builtin_amdgcn_s_setprio(1);                                                         \
    _Pragma("unroll")                                                                      \
    for (int nt = 0; nt < 4; ++nt) {                                                       \
      acc[0][nt] = __builtin_amdgcn_mfma_f32_16x16x32_f16(WC[nt], hv, acc[0][nt], 0, 0, 0);\
      acc[1][nt] = __builtin_amdgcn_mfma_f32_16x16x32_f16(WC[nt], ht, acc[1][nt], 0, 0, 0);\
      acc[2][nt] = __builtin_amdgcn_mfma_f32_16x16x32_f16(WC[nt], hx, acc[2][nt], 0, 0, 0);\
      acc[3][nt] = __builtin_amdgcn_mfma_f32_16x16x32_f16(WC[nt], hy, acc[3][nt], 0, 0, 0);\
      acc[4][nt] = __builtin_amdgcn_mfma_f32_16x16x32_f16(WC[nt], hl, acc[4][nt], 0, 0, 0);\
    }                                                                                      \
    __builtin_amdgcn_s_setprio(0);                                                         \
  }

__global__ __launch_bounds__(256, 3)
void pinn_mfma4(const float* __restrict__ t_in, const float* __restrict__ x_in,
                const float* __restrict__ y_in,
                const float* __restrict__ W0, const float* __restrict__ b0,
                const float* __restrict__ b1, const float* __restrict__ b2,
                const float* __restrict__ b3,
                const float* __restrict__ W4, const float* __restrict__ b4,
                const u16* __restrict__ ws,
                float* __restrict__ out)
{
    __shared__ u16 H[5 * 16 * 256];    // 40960 B
    char* Hb = (char*)H;

    const int tid  = threadIdx.x;
    const int lane = tid & 63;
    const int wv   = tid >> 6;

    // ---- layer 0: 3 -> 256 ----
    {
        int p = tid & 15, c = tid >> 4;
        int g0 = blockIdx.x * 16 + p;
        float tv = t_in[g0], xv = x_in[g0], yv = y_in[g0];
        #pragma unroll
        for (int half = 0; half < 2; ++half) {
            int n0 = c * 16 + half * 8;
            float w0[8], w1[8], w2[8], bb[8];
            #pragma unroll
            for (int q = 0; q < 2; ++q) {
                *(float4*)&w0[q*4] = *(const float4*)&W0[0*256 + n0 + q*4];
                *(float4*)&w1[q*4] = *(const float4*)&W0[1*256 + n0 + q*4];
                *(float4*)&w2[q*4] = *(const float4*)&W0[2*256 + n0 + q*4];
                *(float4*)&bb[q*4] = *(const float4*)&b0[n0 + q*4];
            }
            u16 sv[8], st[8], sx[8], sy[8], sl[8];
            #pragma unroll
            for (int j = 0; j < 8; ++j) {
                float z = tv*w0[j] + xv*w1[j] + yv*w2[j] + bb[j];
                float a = tanh_fast(z);
                float g = 1.f - a*a;
                sv[j] = f2h(a);
                st[j] = f2h(g * w0[j]);
                sx[j] = f2h(g * w1[j]);
                sy[j] = f2h(g * w2[j]);
                sl[j] = f2h(-2.f * a * g * (w1[j]*w1[j] + w2[j]*w2[j]));
            }
            int off = p * 512 + ((c * 32 + half * 16) ^ (p << 4));
            *(u16x8*)(Hb + 0*8192 + off) = *(u16x8*)sv;
            *(u16x8*)(Hb + 1*8192 + off) = *(u16x8*)st;
            *(u16x8*)(Hb + 2*8192 + off) = *(u16x8*)sx;
            *(u16x8*)(Hb + 3*8192 + off) = *(u16x8*)sy;
            *(u16x8*)(Hb + 4*8192 + off) = *(u16x8*)sl;
        }
    }
    __syncthreads();

    const int mrow  = lane & 15;        // point (B-frag row / C col)
    const int kg    = lane >> 4;        // k-group / C row-group
    const int mxor  = mrow << 4;
    const int mbase = mrow * 512;

    // per-thread weight-fragment base pointer (pointer-bump addressing)
    const u16* pWb = ws + wv * 2048 + lane * 8;

    f16x8 whA[4], whB[4];
    #pragma unroll
    for (int nt = 0; nt < 4; ++nt)
        whA[nt] = *(const f16x8*)(pWb + nt * 512);   // L=0, ks=0

    #pragma unroll 1
    for (int L = 0; L < 3; ++L) {
        const float* bL = (L == 0) ? b1 : ((L == 1) ? b2 : b3);

        float4 bv4[4];
        #pragma unroll
        for (int nt = 0; nt < 4; ++nt)
            bv4[nt] = *(const float4*)&bL[(wv * 4 + nt) * 16 + kg * 4];

        f32x4 acc[5][4];
        #pragma unroll
        for (int s = 0; s < 5; ++s)
            #pragma unroll
            for (int nt = 0; nt < 4; ++nt)
                acc[s][nt] = (f32x4){0.f, 0.f, 0.f, 0.f};

        const u16* pL = pWb + L * 65536;
        const int  Ln = (L < 2) ? (L + 1) : 2;
        const u16* pN = pWb + Ln * 65536;

        KSTEP(0, whA, whB, pL + 1*8192);
        KSTEP(1, whB, whA, pL + 2*8192);
        KSTEP(2, whA, whB, pL + 3*8192);
        KSTEP(3, whB, whA, pL + 4*8192);
        KSTEP(4, whA, whB, pL + 5*8192);
        KSTEP(5, whB, whA, pL + 6*8192);
        KSTEP(6, whA, whB, pL + 7*8192);
        KSTEP(7, whB, whA, pN);          // prefetch next layer ks=0

        __syncthreads();   // all H reads of this layer done

        // ---- coupling + write next-layer H ----
        #pragma unroll
        for (int nt = 0; nt < 4; ++nt) {
            int nb = (wv * 4 + nt) * 16 + kg * 4;
            float bva[4] = {bv4[nt].x, bv4[nt].y, bv4[nt].z, bv4[nt].w};
            u16 ov[4], ot4[4], ox4[4], oy4[4], ol4[4];
            #pragma unroll
            for (int r = 0; r < 4; ++r) {
                float z0 = acc[0][nt][r] + bva[r];
                float a  = tanh_fast(z0);
                float g  = 1.f - a * a;
                float zt = acc[1][nt][r];
                float zx = acc[2][nt][r];
                float zy = acc[3][nt][r];
                float zl = acc[4][nt][r];
                ov[r]  = f2h(a);
                ot4[r] = f2h(g * zt);
                ox4[r] = f2h(g * zx);
                oy4[r] = f2h(g * zy);
                ol4[r] = f2h(g * zl - 2.f * a * g * (zx*zx + zy*zy));
            }
            int off = mbase + ((2 * nb) ^ mxor);
            *(u16x4*)(Hb + 0*8192 + off) = *(u16x4*)ov;
            *(u16x4*)(Hb + 1*8192 + off) = *(u16x4*)ot4;
            *(u16x4*)(Hb + 2*8192 + off) = *(u16x4*)ox4;
            *(u16x4*)(Hb + 3*8192 + off) = *(u16x4*)oy4;
            *(u16x4*)(Hb + 4*8192 + off) = *(u16x4*)ol4;
        }
        __syncthreads();
    }

    // ---- final layer: 256 -> 2 (linear, fp32) + PDE residuals ----
    {
        int p = tid >> 4, i = tid & 15;
        float pu = 0.f, pv = 0.f, put = 0.f, pvt = 0.f, plu = 0.f, plv = 0.f;
        #pragma unroll
        for (int half = 0; half < 2; ++half) {
            int k0  = i * 16 + half * 8;
            int off = p * 512 + ((i * 32 + half * 16) ^ (p << 4));
            u16x8 hv = *(const u16x8*)(Hb + 0*8192 + off);
            u16x8 ht = *(const u16x8*)(Hb + 1*8192 + off);
            u16x8 hl = *(const u16x8*)(Hb + 4*8192 + off);
            float w4[16];
            #pragma unroll
            for (int q = 0; q < 4; ++q)
                *(float4*)&w4[q*4] = *(const float4*)&W4[k0 * 2 + q * 4];
            #pragma unroll
            for (int j = 0; j < 8; ++j) {
                float vv = h2f(hv[j]);
                float tt = h2f(ht[j]);
                float ll = h2f(hl[j]);
                float wa = w4[2*j], wb2 = w4[2*j + 1];
                pu  += vv * wa;  pv  += vv * wb2;
                put += tt * wa;  pvt += tt * wb2;
                plu += ll * wa;  plv += ll * wb2;
            }
        }
        #pragma unroll
        for (int m = 1; m < 16; m <<= 1) {
            pu  += __shfl_xor(pu, m);   pv  += __shfl_xor(pv, m);
            put += __shfl_xor(put, m);  pvt += __shfl_xor(pvt, m);
            plu += __shfl_xor(plu, m);  plv += __shfl_xor(plv, m);
        }
        if (i == 0) {
            float u = pu + b4[0];
            float v = pv + b4[1];
            int gpt = blockIdx.x * 16 + p;
            float fo = u - u*u*u - K_CONST - v + D_U * plu - put;
            float go = u - v + D_V * plv - pvt;
            out[0 * N_PTS + gpt] = u;
            out[1 * N_PTS + gpt] = v;
            out[2 * N_PTS + gpt] = fo;
            out[3 * N_PTS + gpt] = go;
        }
    }
}

// ---------------- fallback (round-1 fp32 kernel) if ws too small ----------------
#define PTS   16
#define NTHR  256
#define HDIM  256
#define KC    32
#define HPAD  260

__global__ __launch_bounds__(NTHR, 1)
void pinn_diffreact_f32(const float* __restrict__ t_in, const float* __restrict__ x_in,
                        const float* __restrict__ y_in,
                        const float* __restrict__ W0, const float* __restrict__ b0,
                        const float* __restrict__ W1, const float* __restrict__ b1,
                        const float* __restrict__ W2, const float* __restrict__ b2,
                        const float* __restrict__ W3, const float* __restrict__ b3,
                        const float* __restrict__ W4, const float* __restrict__ b4,
                        float* __restrict__ out)
{
    __shared__ float Hs[6 * PTS * HPAD];
    __shared__ float Wc[KC * HDIM];
    const int tid = threadIdx.x;
    const int pt = tid >> 4;
    const int fbase = (tid & 15) * 4;
    const int gpt = blockIdx.x * PTS + pt;
    {
        const float tv = t_in[gpt], xv = x_in[gpt], yv = y_in[gpt];
        #pragma unroll
        for (int jv = 0; jv < 4; ++jv)
            #pragma unroll
            for (int q = 0; q < 4; ++q) {
                const int f = fbase + jv * 64 + q;
                const float w0 = W0[f], w1 = W0[256 + f], w2 = W0[512 + f];
                const float z = tv*w0 + xv*w1 + yv*w2 + b0[f];
                const float a = tanhf(z), g = 1.f - a*a;
                Hs[(0*PTS+pt)*HPAD+f] = a;
                Hs[(1*PTS+pt)*HPAD+f] = g*w0;
                Hs[(2*PTS+pt)*HPAD+f] = g*w1;
                Hs[(3*PTS+pt)*HPAD+f] = g*w2;
                Hs[(4*PTS+pt)*HPAD+f] = -2.f*a*g*w1*w1;
                Hs[(5*PTS+pt)*HPAD+f] = -2.f*a*g*w2*w2;
            }
    }
    __syncthreads();
    const float* Ws[3] = {W1, W2, W3};
    const float* bs[3] = {b1, b2, b3};
    for (int L = 0; L < 3; ++L) {
        const float* __restrict__ W = Ws[L];
        const float* __restrict__ b = bs[L];
        float acc[6][16];
        #pragma unroll
        for (int s = 0; s < 6; ++s)
            #pragma unroll
            for (int j = 0; j < 16; ++j) acc[s][j] = 0.f;
        for (int kc = 0; kc < HDIM / KC; ++kc) {
            __syncthreads();
            const float4* src = (const float4*)(W + kc * KC * HDIM);
            float4* dst = (float4*)Wc;
            #pragma unroll
            for (int i2 = 0; i2 < (KC * HDIM / 4) / NTHR; ++i2)
                dst[tid + i2 * NTHR] = src[tid + i2 * NTHR];
            __syncthreads();
            #pragma unroll
            for (int k4 = 0; k4 < KC; k4 += 4) {
                float4 h[6];
                #pragma unroll
                for (int s = 0; s < 6; ++s)
                    h[s] = *(const float4*)&Hs[(s*PTS+pt)*HPAD + kc*KC + k4];
                #pragma unroll
                for (int q = 0; q < 4; ++q) {
                    float hv[6];
                    #pragma unroll
                    for (int s = 0; s < 6; ++s)
                        hv[s] = (q==0) ? h[s].x : (q==1) ? h[s].y : (q==2) ? h[s].z : h[s].w;
                    #pragma unroll
                    for (int jv = 0; jv < 4; ++jv) {
                        const float4 wq = *(const float4*)&Wc[(k4+q)*HDIM + fbase + jv*64];
                        const float wvv[4] = {wq.x, wq.y, wq.z, wq.w};
                        #pragma unroll
                        for (int r = 0; r < 4; ++r)
                            #pragma unroll
                            for (int s = 0; s < 6; ++s)
                                acc[s][jv*4+r] += hv[s] * wvv[r];
                    }
                }
            }
        }
        __syncthreads();
        #pragma unroll
        for (int jv = 0; jv < 4; ++jv)
            #pragma unroll
            for (int q = 0; q < 4; ++q) {
                const int j = jv*4+q, f = fbase + jv*64 + q;
                const float z = acc[0][j] + b[f];
                const float a = tanhf(z), g = 1.f - a*a;
                const float zt = acc[1][j], zx = acc[2][j], zy = acc[3][j];
                const float zxx = acc[4][j], zyy = acc[5][j];
                Hs[(0*PTS+pt)*HPAD+f] = a;
                Hs[(1*PTS+pt)*HPAD+f] = g*zt;
                Hs[(2*PTS+pt)*HPAD+f] = g*zx;
                Hs[(3*PTS+pt)*HPAD+f] = g*zy;
                Hs[(4*PTS+pt)*HPAD+f] = g*zxx - 2.f*a*g*zx*zx;
                Hs[(5*PTS+pt)*HPAD+f] = g*zyy - 2.f*a*g*zy*zy;
            }
        __syncthreads();
    }
    float p[6][2];
    #pragma unroll
    for (int s = 0; s < 6; ++s) { p[s][0] = 0.f; p[s][1] = 0.f; }
    #pragma unroll
    for (int jv = 0; jv < 4; ++jv)
        #pragma unroll
        for (int q = 0; q < 4; ++q) {
            const int f = fbase + jv*64 + q;
            const float w0 = W4[f*2], w1 = W4[f*2+1];
            #pragma unroll
            for (int s = 0; s < 6; ++s) {
                const float hv = Hs[(s*PTS+pt)*HPAD+f];
                p[s][0] += hv*w0; p[s][1] += hv*w1;
            }
        }
    #pragma unroll
    for (int m = 1; m < 16; m <<= 1)
        #pragma unroll
        for (int s = 0; s < 6; ++s) {
            p[s][0] += __shfl_xor(p[s][0], m);
            p[s][1] += __shfl_xor(p[s][1], m);
        }
    if ((tid & 15) == 0) {
        const float u = p[0][0] + b4[0];
        const float v = p[0][1] + b4[1];
        const float ut = p[1][0], vt = p[1][1];
        const float uxx = p[4][0], vxx = p[4][1];
        const float uyy = p[5][0], vyy = p[5][1];
        const float fo = u - u*u*u - K_CONST - v + D_U*(uxx+uyy) - ut;
        const float go = u - v + D_V*(vxx+vyy) - vt;
        out[0*N_PTS+gpt] = u;
        out[1*N_PTS+gpt] = v;
        out[2*N_PTS+gpt] = fo;
        out[3*N_PTS+gpt] = go;
    }
}

extern "C" void kernel_launch(void* const* d_in, const int* in_sizes, int n_in,
                              void* d_out, int out_size, void* d_ws, size_t ws_size,
                              hipStream_t stream)
{
    const float* t_in = (const float*)d_in[0];
    const float* x_in = (const float*)d_in[1];
    const float* y_in = (const float*)d_in[2];
    const float* W0 = (const float*)d_in[3];
    const float* b0 = (const float*)d_in[4];
    const float* W1 = (const float*)d_in[5];
    const float* b1 = (const float*)d_in[6];
    const float* W2 = (const float*)d_in[7];
    const float* b2 = (const float*)d_in[8];
    const float* W3 = (const float*)d_in[9];
    const float* b3 = (const float*)d_in[10];
    const float* W4 = (const float*)d_in[11];
    const float* b4 = (const float*)d_in[12];
    float* out = (float*)d_out;

    const size_t WS_NEEDED = (size_t)3 * 8 * 16 * 64 * 8 * 2;  // 393216 B (fp16)
    if (ws_size >= WS_NEEDED) {
        u16* ws = (u16*)d_ws;
        hipLaunchKernelGGL(prep_weights, dim3(96), dim3(256), 0, stream, W1, W2, W3, ws);
        hipLaunchKernelGGL(pinn_mfma4, dim3(N_PTS / 16), dim3(256), 0, stream,
                           t_in, x_in, y_in, W0, b0, b1, b2, b3, W4, b4, ws, out);
    } else {
        hipLaunchKernelGGL(pinn_diffreact_f32, dim3(N_PTS / PTS), dim3(NTHR), 0, stream,
                           t_in, x_in, y_in, W0, b0, W1, b1, W2, b2, W3, b3, W4, b4, out);
    }
}

// Round 6
// 289.859 us; speedup vs baseline: 15.5836x; 1.2200x over previous
//
#include <hip/hip_runtime.h>
#include <math.h>

#define N_PTS   131072
#define K_CONST 0.005f
#define D_U     0.001f
#define D_V     0.005f

typedef unsigned short u16;
typedef __attribute__((ext_vector_type(8))) _Float16 f16x8;
typedef __attribute__((ext_vector_type(4))) float    f32x4;
typedef __attribute__((ext_vector_type(4))) u16      u16x4;
typedef __attribute__((ext_vector_type(8))) u16      u16x8;

__device__ __forceinline__ u16 f2h(float x){
    _Float16 h = (_Float16)x;                 // v_cvt_f16_f32 (RNE)
    return __builtin_bit_cast(u16, h);
}
__device__ __forceinline__ float h2f(u16 h){
    return (float)__builtin_bit_cast(_Float16, h);
}

__device__ __forceinline__ float tanh_fast(float z){
    float e = __expf(2.f * z);
    return 1.f - 2.f * __builtin_amdgcn_rcpf(e + 1.f);
}

// ---------------- prep: W1..W3 -> fp16, W^T fragment layout ----------------
// idx = (((L*8 + ks)*16 + nt)*64 + lane)*8 + j
// val = W[k][n], k = ks*32 + (lane>>4)*8 + j, n = nt*16 + (lane&15)
__global__ void prep_weights(const float* __restrict__ W1, const float* __restrict__ W2,
                             const float* __restrict__ W3, u16* __restrict__ ws)
{
    int gid  = blockIdx.x * 256 + threadIdx.x;   // 0 .. 24575
    int lane = gid & 63;
    int nt   = (gid >> 6) & 15;
    int ks   = (gid >> 10) & 7;
    int L    = gid >> 13;
    if (L >= 3) return;
    const float* W = (L == 0) ? W1 : ((L == 1) ? W2 : W3);
    int n  = nt * 16 + (lane & 15);
    int kg = lane >> 4;
    u16 h[8];
    #pragma unroll
    for (int j = 0; j < 8; ++j) {
        int k = ks * 32 + kg * 8 + j;
        h[j] = f2h(W[k * 256 + n]);
    }
    *(u16x8*)&ws[(size_t)gid * 8] = *(u16x8*)h;
}

// ---------------- main fused kernel ----------------
// Block: 16 points, 4 waves. 5 LDS planes [16 pts][256 feats] fp16, XOR-swizzled:
//   byte(plane,m,k) = plane*8192 + m*512 + ((2k) ^ ((m&15)<<4))
// planes: 0=value 1=d/dt 2=d/dx 3=d/dy 4=laplacian
// Per (nt,ks): 5 MFMA (one per stream), fp16 single-pass.
// C layout: row = n-in-tile = (lane>>4)*4+r, col = point = lane&15.
// launch_bounds(256,2): 256-reg budget. (256,3) caps at ~168 -> ~84 VGPR + 84 AGPR
// split -> non-acc side spills to scratch (R5: 500 MB HBM writeback, MfmaUtil 32%).

#define KSTEP(KS, WC, WN, PN)                                                              \
  {                                                                                        \
    _Pragma("unroll")                                                                      \
    for (int nt = 0; nt < 4; ++nt)                                                         \
      WN[nt] = *(const f16x8*)((PN) + nt * 512);                                           \
    int hoff = mbase + ((64 * (KS) + 16 * kg) ^ mxor);                                     \
    f16x8 hv = *(const f16x8*)(Hb + 0 * 8192 + hoff);                                      \
    f16x8 ht = *(const f16x8*)(Hb + 1 * 8192 + hoff);                                      \
    f16x8 hx = *(const f16x8*)(Hb + 2 * 8192 + hoff);                                      \
    f16x8 hy = *(const f16x8*)(Hb + 3 * 8192 + hoff);                                      \
    f16x8 hl = *(const f16x8*)(Hb + 4 * 8192 + hoff);                                      \
    __builtin_amdgcn_s_setprio(1);                                                         \
    _Pragma("unroll")                                                                      \
    for (int nt = 0; nt < 4; ++nt) {                                                       \
      acc[0][nt] = __builtin_amdgcn_mfma_f32_16x16x32_f16(WC[nt], hv, acc[0][nt], 0, 0, 0);\
      acc[1][nt] = __builtin_amdgcn_mfma_f32_16x16x32_f16(WC[nt], ht, acc[1][nt], 0, 0, 0);\
      acc[2][nt] = __builtin_amdgcn_mfma_f32_16x16x32_f16(WC[nt], hx, acc[2][nt], 0, 0, 0);\
      acc[3][nt] = __builtin_amdgcn_mfma_f32_16x16x32_f16(WC[nt], hy, acc[3][nt], 0, 0, 0);\
      acc[4][nt] = __builtin_amdgcn_mfma_f32_16x16x32_f16(WC[nt], hl, acc[4][nt], 0, 0, 0);\
    }                                                                                      \
    __builtin_amdgcn_s_setprio(0);                                                         \
  }

__global__ __launch_bounds__(256, 2)
void pinn_mfma5(const float* __restrict__ t_in, const float* __restrict__ x_in,
                const float* __restrict__ y_in,
                const float* __restrict__ W0, const float* __restrict__ b0,
                const float* __restrict__ b1, const float* __restrict__ b2,
                const float* __restrict__ b3,
                const float* __restrict__ W4, const float* __restrict__ b4,
                const u16* __restrict__ ws,
                float* __restrict__ out)
{
    __shared__ u16 H[5 * 16 * 256];    // 40960 B
    char* Hb = (char*)H;

    const int tid  = threadIdx.x;
    const int lane = tid & 63;
    const int wv   = tid >> 6;

    // ---- layer 0: 3 -> 256 ----
    {
        int p = tid & 15, c = tid >> 4;
        int g0 = blockIdx.x * 16 + p;
        float tv = t_in[g0], xv = x_in[g0], yv = y_in[g0];
        #pragma unroll
        for (int half = 0; half < 2; ++half) {
            int n0 = c * 16 + half * 8;
            float w0[8], w1[8], w2[8], bb[8];
            #pragma unroll
            for (int q = 0; q < 2; ++q) {
                *(float4*)&w0[q*4] = *(const float4*)&W0[0*256 + n0 + q*4];
                *(float4*)&w1[q*4] = *(const float4*)&W0[1*256 + n0 + q*4];
                *(float4*)&w2[q*4] = *(const float4*)&W0[2*256 + n0 + q*4];
                *(float4*)&bb[q*4] = *(const float4*)&b0[n0 + q*4];
            }
            u16 sv[8], st[8], sx[8], sy[8], sl[8];
            #pragma unroll
            for (int j = 0; j < 8; ++j) {
                float z = tv*w0[j] + xv*w1[j] + yv*w2[j] + bb[j];
                float a = tanh_fast(z);
                float g = 1.f - a*a;
                sv[j] = f2h(a);
                st[j] = f2h(g * w0[j]);
                sx[j] = f2h(g * w1[j]);
                sy[j] = f2h(g * w2[j]);
                sl[j] = f2h(-2.f * a * g * (w1[j]*w1[j] + w2[j]*w2[j]));
            }
            int off = p * 512 + ((c * 32 + half * 16) ^ (p << 4));
            *(u16x8*)(Hb + 0*8192 + off) = *(u16x8*)sv;
            *(u16x8*)(Hb + 1*8192 + off) = *(u16x8*)st;
            *(u16x8*)(Hb + 2*8192 + off) = *(u16x8*)sx;
            *(u16x8*)(Hb + 3*8192 + off) = *(u16x8*)sy;
            *(u16x8*)(Hb + 4*8192 + off) = *(u16x8*)sl;
        }
    }
    __syncthreads();

    const int mrow  = lane & 15;        // point (B-frag row / C col)
    const int kg    = lane >> 4;        // k-group / C row-group
    const int mxor  = mrow << 4;
    const int mbase = mrow * 512;

    // per-thread weight-fragment base pointer (pointer-bump addressing)
    const u16* pWb = ws + wv * 2048 + lane * 8;

    f16x8 whA[4], whB[4];
    #pragma unroll
    for (int nt = 0; nt < 4; ++nt)
        whA[nt] = *(const f16x8*)(pWb + nt * 512);   // L=0, ks=0

    #pragma unroll 1
    for (int L = 0; L < 3; ++L) {
        const float* bL = (L == 0) ? b1 : ((L == 1) ? b2 : b3);

        f32x4 acc[5][4];
        #pragma unroll
        for (int s = 0; s < 5; ++s)
            #pragma unroll
            for (int nt = 0; nt < 4; ++nt)
                acc[s][nt] = (f32x4){0.f, 0.f, 0.f, 0.f};

        const u16* pL = pWb + L * 65536;
        const int  Ln = (L < 2) ? (L + 1) : 2;
        const u16* pN = pWb + Ln * 65536;

        KSTEP(0, whA, whB, pL + 1*8192);
        KSTEP(1, whB, whA, pL + 2*8192);
        KSTEP(2, whA, whB, pL + 3*8192);
        KSTEP(3, whB, whA, pL + 4*8192);
        KSTEP(4, whA, whB, pL + 5*8192);
        KSTEP(5, whB, whA, pL + 6*8192);
        KSTEP(6, whA, whB, pL + 7*8192);
        KSTEP(7, whB, whA, pN);          // prefetch next layer ks=0

        __syncthreads();   // all H reads of this layer done

        // ---- coupling + write next-layer H ----
        #pragma unroll
        for (int nt = 0; nt < 4; ++nt) {
            int nb = (wv * 4 + nt) * 16 + kg * 4;
            float4 bv = *(const float4*)&bL[nb];   // L2-hot, once per layer
            float bva[4] = {bv.x, bv.y, bv.z, bv.w};
            u16 ov[4], ot4[4], ox4[4], oy4[4], ol4[4];
            #pragma unroll
            for (int r = 0; r < 4; ++r) {
                float z0 = acc[0][nt][r] + bva[r];
                float a  = tanh_fast(z0);
                float g  = 1.f - a * a;
                float zt = acc[1][nt][r];
                float zx = acc[2][nt][r];
                float zy = acc[3][nt][r];
                float zl = acc[4][nt][r];
                ov[r]  = f2h(a);
                ot4[r] = f2h(g * zt);
                ox4[r] = f2h(g * zx);
                oy4[r] = f2h(g * zy);
                ol4[r] = f2h(g * zl - 2.f * a * g * (zx*zx + zy*zy));
            }
            int off = mbase + ((2 * nb) ^ mxor);
            *(u16x4*)(Hb + 0*8192 + off) = *(u16x4*)ov;
            *(u16x4*)(Hb + 1*8192 + off) = *(u16x4*)ot4;
            *(u16x4*)(Hb + 2*8192 + off) = *(u16x4*)ox4;
            *(u16x4*)(Hb + 3*8192 + off) = *(u16x4*)oy4;
            *(u16x4*)(Hb + 4*8192 + off) = *(u16x4*)ol4;
        }
        __syncthreads();
    }

    // ---- final layer: 256 -> 2 (linear, fp32) + PDE residuals ----
    {
        int p = tid >> 4, i = tid & 15;
        float pu = 0.f, pv = 0.f, put = 0.f, pvt = 0.f, plu = 0.f, plv = 0.f;
        #pragma unroll
        for (int half = 0; half < 2; ++half) {
            int k0  = i * 16 + half * 8;
            int off = p * 512 + ((i * 32 + half * 16) ^ (p << 4));
            u16x8 hv = *(const u16x8*)(Hb + 0*8192 + off);
            u16x8 ht = *(const u16x8*)(Hb + 1*8192 + off);
            u16x8 hl = *(const u16x8*)(Hb + 4*8192 + off);
            float w4[16];
            #pragma unroll
            for (int q = 0; q < 4; ++q)
                *(float4*)&w4[q*4] = *(const float4*)&W4[k0 * 2 + q * 4];
            #pragma unroll
            for (int j = 0; j < 8; ++j) {
                float vv = h2f(hv[j]);
                float tt = h2f(ht[j]);
                float ll = h2f(hl[j]);
                float wa = w4[2*j], wb2 = w4[2*j + 1];
                pu  += vv * wa;  pv  += vv * wb2;
                put += tt * wa;  pvt += tt * wb2;
                plu += ll * wa;  plv += ll * wb2;
            }
        }
        #pragma unroll
        for (int m = 1; m < 16; m <<= 1) {
            pu  += __shfl_xor(pu, m);   pv  += __shfl_xor(pv, m);
            put += __shfl_xor(put, m);  pvt += __shfl_xor(pvt, m);
            plu += __shfl_xor(plu, m);  plv += __shfl_xor(plv, m);
        }
        if (i == 0) {
            float u = pu + b4[0];
            float v = pv + b4[1];
            int gpt = blockIdx.x * 16 + p;
            float fo = u - u*u*u - K_CONST - v + D_U * plu - put;
            float go = u - v + D_V * plv - pvt;
            out[0 * N_PTS + gpt] = u;
            out[1 * N_PTS + gpt] = v;
            out[2 * N_PTS + gpt] = fo;
            out[3 * N_PTS + gpt] = go;
        }
    }
}

// ---------------- fallback (round-1 fp32 kernel) if ws too small ----------------
#define PTS   16
#define NTHR  256
#define HDIM  256
#define KC    32
#define HPAD  260

__global__ __launch_bounds__(NTHR, 1)
void pinn_diffreact_f32(const float* __restrict__ t_in, const float* __restrict__ x_in,
                        const float* __restrict__ y_in,
                        const float* __restrict__ W0, const float* __restrict__ b0,
                        const float* __restrict__ W1, const float* __restrict__ b1,
                        const float* __restrict__ W2, const float* __restrict__ b2,
                        const float* __restrict__ W3, const float* __restrict__ b3,
                        const float* __restrict__ W4, const float* __restrict__ b4,
                        float* __restrict__ out)
{
    __shared__ float Hs[6 * PTS * HPAD];
    __shared__ float Wc[KC * HDIM];
    const int tid = threadIdx.x;
    const int pt = tid >> 4;
    const int fbase = (tid & 15) * 4;
    const int gpt = blockIdx.x * PTS + pt;
    {
        const float tv = t_in[gpt], xv = x_in[gpt], yv = y_in[gpt];
        #pragma unroll
        for (int jv = 0; jv < 4; ++jv)
            #pragma unroll
            for (int q = 0; q < 4; ++q) {
                const int f = fbase + jv * 64 + q;
                const float w0 = W0[f], w1 = W0[256 + f], w2 = W0[512 + f];
                const float z = tv*w0 + xv*w1 + yv*w2 + b0[f];
                const float a = tanhf(z), g = 1.f - a*a;
                Hs[(0*PTS+pt)*HPAD+f] = a;
                Hs[(1*PTS+pt)*HPAD+f] = g*w0;
                Hs[(2*PTS+pt)*HPAD+f] = g*w1;
                Hs[(3*PTS+pt)*HPAD+f] = g*w2;
                Hs[(4*PTS+pt)*HPAD+f] = -2.f*a*g*w1*w1;
                Hs[(5*PTS+pt)*HPAD+f] = -2.f*a*g*w2*w2;
            }
    }
    __syncthreads();
    const float* Ws[3] = {W1, W2, W3};
    const float* bs[3] = {b1, b2, b3};
    for (int L = 0; L < 3; ++L) {
        const float* __restrict__ W = Ws[L];
        const float* __restrict__ b = bs[L];
        float acc[6][16];
        #pragma unroll
        for (int s = 0; s < 6; ++s)
            #pragma unroll
            for (int j = 0; j < 16; ++j) acc[s][j] = 0.f;
        for (int kc = 0; kc < HDIM / KC; ++kc) {
            __syncthreads();
            const float4* src = (const float4*)(W + kc * KC * HDIM);
            float4* dst = (float4*)Wc;
            #pragma unroll
            for (int i2 = 0; i2 < (KC * HDIM / 4) / NTHR; ++i2)
                dst[tid + i2 * NTHR] = src[tid + i2 * NTHR];
            __syncthreads();
            #pragma unroll
            for (int k4 = 0; k4 < KC; k4 += 4) {
                float4 h[6];
                #pragma unroll
                for (int s = 0; s < 6; ++s)
                    h[s] = *(const float4*)&Hs[(s*PTS+pt)*HPAD + kc*KC + k4];
                #pragma unroll
                for (int q = 0; q < 4; ++q) {
                    float hv[6];
                    #pragma unroll
                    for (int s = 0; s < 6; ++s)
                        hv[s] = (q==0) ? h[s].x : (q==1) ? h[s].y : (q==2) ? h[s].z : h[s].w;
                    #pragma unroll
                    for (int jv = 0; jv < 4; ++jv) {
                        const float4 wq = *(const float4*)&Wc[(k4+q)*HDIM + fbase + jv*64];
                        const float wvv[4] = {wq.x, wq.y, wq.z, wq.w};
                        #pragma unroll
                        for (int r = 0; r < 4; ++r)
                            #pragma unroll
                            for (int s = 0; s < 6; ++s)
                                acc[s][jv*4+r] += hv[s] * wvv[r];
                    }
                }
            }
        }
        __syncthreads();
        #pragma unroll
        for (int jv = 0; jv < 4; ++jv)
            #pragma unroll
            for (int q = 0; q < 4; ++q) {
                const int j = jv*4+q, f = fbase + jv*64 + q;
                const float z = acc[0][j] + b[f];
                const float a = tanhf(z), g = 1.f - a*a;
                const float zt = acc[1][j], zx = acc[2][j], zy = acc[3][j];
                const float zxx = acc[4][j], zyy = acc[5][j];
                Hs[(0*PTS+pt)*HPAD+f] = a;
                Hs[(1*PTS+pt)*HPAD+f] = g*zt;
                Hs[(2*PTS+pt)*HPAD+f] = g*zx;
                Hs[(3*PTS+pt)*HPAD+f] = g*zy;
                Hs[(4*PTS+pt)*HPAD+f] = g*zxx - 2.f*a*g*zx*zx;
                Hs[(5*PTS+pt)*HPAD+f] = g*zyy - 2.f*a*g*zy*zy;
            }
        __syncthreads();
    }
    float p[6][2];
    #pragma unroll
    for (int s = 0; s < 6; ++s) { p[s][0] = 0.f; p[s][1] = 0.f; }
    #pragma unroll
    for (int jv = 0; jv < 4; ++jv)
        #pragma unroll
        for (int q = 0; q < 4; ++q) {
            const int f = fbase + jv*64 + q;
            const float w0 = W4[f*2], w1 = W4[f*2+1];
            #pragma unroll
            for (int s = 0; s < 6; ++s) {
                const float hv = Hs[(s*PTS+pt)*HPAD+f];
                p[s][0] += hv*w0; p[s][1] += hv*w1;
            }
        }
    #pragma unroll
    for (int m = 1; m < 16; m <<= 1)
        #pragma unroll
        for (int s = 0; s < 6; ++s) {
            p[s][0] += __shfl_xor(p[s][0], m);
            p[s][1] += __shfl_xor(p[s][1], m);
        }
    if ((tid & 15) == 0) {
        const float u = p[0][0] + b4[0];
        const float v = p[0][1] + b4[1];
        const float ut = p[1][0], vt = p[1][1];
        const float uxx = p[4][0], vxx = p[4][1];
        const float uyy = p[5][0], vyy = p[5][1];
        const float fo = u - u*u*u - K_CONST - v + D_U*(uxx+uyy) - ut;
        const float go = u - v + D_V*(vxx+vyy) - vt;
        out[0*N_PTS+gpt] = u;
        out[1*N_PTS+gpt] = v;
        out[2*N_PTS+gpt] = fo;
        out[3*N_PTS+gpt] = go;
    }
}

extern "C" void kernel_launch(void* const* d_in, const int* in_sizes, int n_in,
                              void* d_out, int out_size, void* d_ws, size_t ws_size,
                              hipStream_t stream)
{
    const float* t_in = (const float*)d_in[0];
    const float* x_in = (const float*)d_in[1];
    const float* y_in = (const float*)d_in[2];
    const float* W0 = (const float*)d_in[3];
    const float* b0 = (const float*)d_in[4];
    const float* W1 = (const float*)d_in[5];
    const float* b1 = (const float*)d_in[6];
    const float* W2 = (const float*)d_in[7];
    const float* b2 = (const float*)d_in[8];
    const float* W3 = (const float*)d_in[9];
    const float* b3 = (const float*)d_in[10];
    const float* W4 = (const float*)d_in[11];
    const float* b4 = (const float*)d_in[12];
    float* out = (float*)d_out;

    const size_t WS_NEEDED = (size_t)3 * 8 * 16 * 64 * 8 * 2;  // 393216 B (fp16)
    if (ws_size >= WS_NEEDED) {
        u16* ws = (u16*)d_ws;
        hipLaunchKernelGGL(prep_weights, dim3(96), dim3(256), 0, stream, W1, W2, W3, ws);
        hipLaunchKernelGGL(pinn_mfma5, dim3(N_PTS / 16), dim3(256), 0, stream,
                           t_in, x_in, y_in, W0, b0, b1, b2, b3, W4, b4, ws, out);
    } else {
        hipLaunchKernelGGL(pinn_diffreact_f32, dim3(N_PTS / PTS), dim3(NTHR), 0, stream,
                           t_in, x_in, y_in, W0, b0, W1, b1, W2, b2, W3, b3, W4, b4, out);
    }
}